// Round 6
// baseline (301.473 us; speedup 1.0000x reference)
//
#include <hip/hip_runtime.h>

#define SEQ   2048
#define NHEAD 16
#define DKK   64
#define HID   1024

typedef __attribute__((ext_vector_type(8))) short bf16x8;
typedef __attribute__((ext_vector_type(4))) float f32x4;

__device__ __forceinline__ unsigned short f32_bf16(float f) {
    unsigned int u = __builtin_bit_cast(unsigned int, f);
    u += 0x7fffu + ((u >> 16) & 1u);
    return (unsigned short)(u >> 16);
}

// one-instruction packed f32x2 -> bf16x2 (RNE), per T12 recipe
__device__ __forceinline__ unsigned int cvt_pk_bf16(float lo, float hi) {
    unsigned int r;
    asm("v_cvt_pk_bf16_f32 %0, %1, %2" : "=v"(r) : "v"(lo), "v"(hi));
    return r;
}

// raw v_exp_f32 (2^x). Scores bounded (|x| < ~45), no range reduction needed.
__device__ __forceinline__ float fast_exp2(float x) {
    float r;
    asm("v_exp_f32 %0, %1" : "=v"(r) : "v"(x));
    return r;
}

// async global->LDS 16B copy (DMA, no VGPR round-trip)
__device__ __forceinline__ void glds16(const void* g, void* l) {
    __builtin_amdgcn_global_load_lds(
        (const __attribute__((address_space(1))) unsigned int*)g,
        (__attribute__((address_space(3))) unsigned int*)l, 16, 0, 0);
}

// ---------------------------------------------------------------------------
// Kernel A: fused prep — fp32->bf16 convert of all 7 tensors + mask bit-pack
// via wave ballot (coalesced lane reads; __ballot IS the packed word).
// ---------------------------------------------------------------------------
__global__ __launch_bounds__(256)
void prep_kernel(const float* __restrict__ q, const float* __restrict__ k,
                 const float* __restrict__ v,
                 const float* __restrict__ Wq, const float* __restrict__ Wk,
                 const float* __restrict__ Wv, const float* __restrict__ Wo,
                 const int* __restrict__ mask,
                 unsigned short* __restrict__ ws, unsigned long long* __restrict__ Mb)
{
    const int bid = blockIdx.x;
    if (bid < 16384) {
        int i = bid * 256 + threadIdx.x;            // float4 index
        const float* src; int off;
        if (i < 1048576)      { src = q;  off = i; }
        else if (i < 2097152) { src = k;  off = i - 1048576; }
        else if (i < 3145728) { src = v;  off = i - 2097152; }
        else if (i < 3407872) { src = Wq; off = i - 3145728; }
        else if (i < 3670016) { src = Wk; off = i - 3407872; }
        else if (i < 3932160) { src = Wv; off = i - 3670016; }
        else                  { src = Wo; off = i - 3932160; }
        float4 a = ((const float4*)src)[off];
        ((uint2*)ws)[i] = make_uint2(cvt_pk_bf16(a.x, a.y), cvt_pk_bf16(a.z, a.w));
    } else {
        // wave g packs 64 words; word j from 64 coalesced ints via ballot
        const int g    = (bid - 16384) * 4 + (threadIdx.x >> 6);   // 0..2047
        const int lane = threadIdx.x & 63;
        const int* src = mask + (size_t)g * 4096;
        unsigned long long* dstw = Mb + (size_t)g * 64;
        #pragma unroll 4
        for (int j = 0; j < 64; ++j) {
            int m = src[j * 64 + lane];
            unsigned long long wv = __ballot(m != 0);
            if (lane == 0) dstw[j] = wv;
        }
    }
}

// ---------------------------------------------------------------------------
// Kernel 1: QKV projections (round-4 verified form: double-buffered LDS,
// one __syncthreads per K-step).  Q pre-scaled by 0.125*log2(e).  z=2 (V)
// writes coalesced [b,h,s,d] into scratch Vh; vtrans builds Vt[d][s].
// ---------------------------------------------------------------------------
__global__ __launch_bounds__(256, 2)
void proj_kernel(const unsigned short* __restrict__ xq, const unsigned short* __restrict__ xk,
                 const unsigned short* __restrict__ xv,
                 const unsigned short* __restrict__ Wqb, const unsigned short* __restrict__ Wkb,
                 const unsigned short* __restrict__ Wvb,
                 const float* __restrict__ bq_, const float* __restrict__ bk_,
                 const float* __restrict__ bv_,
                 unsigned short* __restrict__ Qh, unsigned short* __restrict__ Kh,
                 unsigned short* __restrict__ Vh)
{
    const int z = blockIdx.z;
    const unsigned short* X; const unsigned short* W; const float* bias;
    if (z == 0)      { X = xq; W = Wqb; bias = bq_; }
    else if (z == 1) { X = xk; W = Wkb; bias = bk_; }
    else             { X = xv; W = Wvb; bias = bv_; }

    const int m0 = blockIdx.x * 128;
    const int n0 = blockIdx.y * 128;
    const int tid  = threadIdx.x;
    const int lane = tid & 63, wid = tid >> 6;
    const int wm = (wid >> 1) * 64, wn = (wid & 1) * 64;
    const int l15 = lane & 15, quad = lane >> 4;

    __shared__ __align__(16) unsigned short As[2][128 * 32];   // 2 x 8 KB
    __shared__ __align__(16) unsigned short Bs[2][128 * 32];

    const int r0 = tid >> 2, cg = tid & 3;
    const unsigned short* gA = X + (size_t)(m0 + r0) * HID + ((cg ^ (r0 & 3)) * 8);
    const unsigned short* gB = W + (size_t)(n0 + r0) * HID + ((cg ^ (r0 & 3)) * 8);

    const int cgsel = (quad ^ (l15 & 3)) * 8;

    f32x4 acc[4][4];
    #pragma unroll
    for (int i = 0; i < 4; ++i)
        #pragma unroll
        for (int j = 0; j < 4; ++j)
            acc[i][j] = f32x4{0.f, 0.f, 0.f, 0.f};

    // prologue: stage k0=0 into buf 0
    glds16(gA, &As[0][tid * 8]);
    glds16(gA + (size_t)64 * HID, &As[0][(tid + 256) * 8]);
    glds16(gB, &Bs[0][tid * 8]);
    glds16(gB + (size_t)64 * HID, &Bs[0][(tid + 256) * 8]);
    __syncthreads();

    for (int k0 = 0; k0 < HID; k0 += 32) {
        const int cur = (k0 >> 5) & 1;
        if (k0 + 32 < HID) {                       // prefetch next K-step
            const int nb = cur ^ 1;
            glds16(gA + k0 + 32, &As[nb][tid * 8]);
            glds16(gA + (size_t)64 * HID + k0 + 32, &As[nb][(tid + 256) * 8]);
            glds16(gB + k0 + 32, &Bs[nb][tid * 8]);
            glds16(gB + (size_t)64 * HID + k0 + 32, &Bs[nb][(tid + 256) * 8]);
        }

        bf16x8 af[4], bfr[4];
        #pragma unroll
        for (int mi = 0; mi < 4; ++mi)
            af[mi] = *(const bf16x8*)&As[cur][(wm + mi * 16 + l15) * 32 + cgsel];
        #pragma unroll
        for (int ni = 0; ni < 4; ++ni)
            bfr[ni] = *(const bf16x8*)&Bs[cur][(wn + ni * 16 + l15) * 32 + cgsel];
        __builtin_amdgcn_s_setprio(1);
        #pragma unroll
        for (int mi = 0; mi < 4; ++mi)
            #pragma unroll
            for (int ni = 0; ni < 4; ++ni)
                acc[mi][ni] = __builtin_amdgcn_mfma_f32_16x16x32_bf16(
                    af[mi], bfr[ni], acc[mi][ni], 0, 0, 0);
        __builtin_amdgcn_s_setprio(0);
        __syncthreads();                           // reads done + prefetch drained
    }

    const float QSCALE = 0.18033688f;   // 0.125 * log2(e)
    #pragma unroll
    for (int mi = 0; mi < 4; ++mi) {
        #pragma unroll
        for (int ni = 0; ni < 4; ++ni) {
            int n = n0 + wn + ni * 16 + l15;
            float bv = bias[n];
            int hh = n >> 6, d = n & 63;
            #pragma unroll
            for (int r = 0; r < 4; ++r) {
                int m = m0 + wm + mi * 16 + quad * 4 + r;
                int bb = m >> 11, s = m & 2047;
                float val = acc[mi][ni][r] + bv;
                if (z == 0)
                    Qh[((size_t)(bb * NHEAD + hh) * SEQ + s) * DKK + d] = f32_bf16(val * QSCALE);
                else if (z == 1)
                    Kh[((size_t)(bb * NHEAD + hh) * SEQ + s) * DKK + d] = f32_bf16(val);
                else
                    Vh[((size_t)(bb * NHEAD + hh) * SEQ + s) * DKK + d] = f32_bf16(val);
            }
        }
    }
}

// ---------------------------------------------------------------------------
// Kernel 1b: Vh[b,h,s,d] -> Vt[b,h,d,s] transpose (round-4 verified).
// ---------------------------------------------------------------------------
__global__ __launch_bounds__(256)
void vtrans_kernel(const unsigned short* __restrict__ Vh, unsigned short* __restrict__ Vt)
{
    __shared__ unsigned int T[64 * 32];
    const int bh = blockIdx.y;
    const int s0 = blockIdx.x * 64;
    const int tid = threadIdx.x;
    const unsigned short* src = Vh + ((size_t)bh * SEQ + s0) * DKK;
    unsigned short* dst = Vt + (size_t)bh * DKK * SEQ + s0;

    #pragma unroll
    for (int j = 0; j < 2; ++j) {
        int i = tid + j * 256;
        int s = i >> 3, ch = i & 7;                // 16B chunk: d = ch*8..+7
        uint4 d4 = *(const uint4*)(src + (size_t)s * DKK + ch * 8);
        *(uint4*)&T[s * 32 + 4 * (ch ^ (s >> 3))] = d4;
    }
    __syncthreads();
    #pragma unroll
    for (int j = 0; j < 2; ++j) {
        int i = tid + j * 256;
        int d = i >> 3, sb = (i & 7) * 8;          // 8 consecutive s at row d
        int d2 = d >> 1, hi = d & 1;
        int g = d2 >> 2, w4 = d2 & 3;
        unsigned int r[8];
        #pragma unroll
        for (int kk = 0; kk < 8; ++kk) {
            int s = sb + kk;
            r[kk] = T[s * 32 + 4 * (g ^ (s >> 3)) + w4];
        }
        uint4 ov;
        if (hi) {
            ov.x = (r[0] >> 16) | (r[1] & 0xffff0000u);
            ov.y = (r[2] >> 16) | (r[3] & 0xffff0000u);
            ov.z = (r[4] >> 16) | (r[5] & 0xffff0000u);
            ov.w = (r[6] >> 16) | (r[7] & 0xffff0000u);
        } else {
            ov.x = (r[0] & 0xffffu) | (r[1] << 16);
            ov.y = (r[2] & 0xffffu) | (r[3] << 16);
            ov.z = (r[4] & 0xffffu) | (r[5] << 16);
            ov.w = (r[6] & 0xffffu) | (r[7] << 16);
        }
        *(uint4*)(dst + (size_t)d * SEQ + sb) = ov;
    }
}

// ---------------------------------------------------------------------------
// Kernel 2: flash attention, swapped-QK^T, QBLK=128 (wave owns 32 q-rows in
// 2 groups of 16).  Per K/V tile: 34 MFMA vs 18 at QBLK=64 against the SAME
// 16 KB staging -> barrier-drain stall amortized 2x; V-fragments loaded once
// and consumed by both groups; K/V total re-fetch halves (512 blocks).
// LDS = 2*8K (K) + 2*8K (V) + 4*2*2K (P) = 48 KB.
// ---------------------------------------------------------------------------
__global__ __launch_bounds__(256, 2)
void attn_kernel(const unsigned short* __restrict__ Qh, const unsigned short* __restrict__ Kh,
                 const unsigned short* __restrict__ Vt,
                 const unsigned long long* __restrict__ Mb,
                 unsigned short* __restrict__ Om)
{
    const int qt = blockIdx.x;       // 0..15
    const int h  = blockIdx.y;
    const int b  = blockIdx.z;
    const int tid  = threadIdx.x;
    const int lane = tid & 63, w = tid >> 6;
    const int l15 = lane & 15, quad = lane >> 4;
    const int q0 = qt * 128;

    const size_t hoff = (size_t)(b * NHEAD + h) * SEQ * DKK;
    const unsigned short* Qp = Qh + hoff;
    const unsigned short* Kp = Kh + hoff;
    const unsigned short* Vp = Vt + hoff;   // [d][s]

    __shared__ __align__(16) unsigned short Ks[2][64 * 64];
    __shared__ __align__(16) unsigned short Vs[2][64 * 64];
    __shared__ __align__(16) unsigned short Ps[4][2][16 * 64];

    // staging: chunk c (16B) for c = tid, tid+256; row = c>>3, sub = c&7;
    // LDS slot (row,sub) holds global chunk (row, sub ^ (row&7)).
    const int sr0 = tid >> 3, ss0 = tid & 7;
    const int sr1 = sr0 + 32;
    const unsigned short* Kg0 = Kp + sr0 * DKK + ((ss0 ^ (sr0 & 7)) * 8);
    const unsigned short* Kg1 = Kp + sr1 * DKK + ((ss0 ^ (sr1 & 7)) * 8);
    const unsigned short* Vg0 = Vp + (size_t)sr0 * SEQ + ((ss0 ^ (sr0 & 7)) * 8);
    const unsigned short* Vg1 = Vp + (size_t)sr1 * SEQ + ((ss0 ^ (sr1 & 7)) * 8);

    const int swz0 = ((0 * 4 + quad) ^ (l15 & 7)) * 8;
    const int swz1 = ((1 * 4 + quad) ^ (l15 & 7)) * 8;

    const int xsw = l15 & 14;
    int wadr[4];
    #pragma unroll
    for (int ni = 0; ni < 4; ++ni)
        wadr[ni] = l15 * 64 + (((ni * 4 + quad) ^ xsw) * 4);
    const int padr0 = l15 * 64 + (((quad * 2) ^ xsw) * 4);
    const int padr1 = l15 * 64 + (((8 + quad * 2) ^ xsw) * 4);

    glds16(Kg0, &Ks[0][tid * 8]);
    glds16(Kg1, &Ks[0][2048 + tid * 8]);
    glds16(Vg0, &Vs[0][tid * 8]);
    glds16(Vg1, &Vs[0][2048 + tid * 8]);

    // Q fragments: wave w owns rows q0 + w*32 + g*16 .. +15, g = 0,1
    bf16x8 qf[2][2];
    #pragma unroll
    for (int g = 0; g < 2; ++g)
        #pragma unroll
        for (int kc = 0; kc < 2; ++kc)
            qf[g][kc] = *(const bf16x8*)(Qp + (size_t)(q0 + w * 32 + g * 16 + l15) * DKK
                                         + kc * 32 + quad * 8);

    bf16x8 onesf;
    #pragma unroll
    for (int i = 0; i < 8; ++i) onesf[i] = (short)0x3F80;

    f32x4 o_acc[2][4];
    f32x4 l_acc[2];
    #pragma unroll
    for (int g = 0; g < 2; ++g) {
        l_acc[g] = f32x4{0.f, 0.f, 0.f, 0.f};
        #pragma unroll
        for (int nd = 0; nd < 4; ++nd) o_acc[g][nd] = f32x4{0.f, 0.f, 0.f, 0.f};
    }

    const unsigned long long* Mrow0 =
        Mb + ((size_t)b * SEQ + q0 + w * 32 + l15) * (SEQ / 64);
    const unsigned long long* Mrow1 = Mrow0 + (size_t)16 * (SEQ / 64);
    unsigned long long mw0 = Mrow0[0], mw1 = Mrow1[0];

    __syncthreads();                       // tile 0 staged

    for (int kt = 0; kt < SEQ / 64; ++kt) {
        const int cur = kt & 1;
        unsigned long long mw0n = 0ull, mw1n = 0ull;
        if (kt < SEQ / 64 - 1) {           // prefetch next tile into other buf
            const int nb = cur ^ 1;
            glds16(Kg0 + (kt + 1) * 64 * DKK, &Ks[nb][tid * 8]);
            glds16(Kg1 + (kt + 1) * 64 * DKK, &Ks[nb][2048 + tid * 8]);
            glds16(Vg0 + (kt + 1) * 64,       &Vs[nb][tid * 8]);
            glds16(Vg1 + (kt + 1) * 64,       &Vs[nb][2048 + tid * 8]);
            mw0n = Mrow0[kt + 1];
            mw1n = Mrow1[kt + 1];
        }

        // QK^T, swapped operands; kb shared across both q-groups
        f32x4 st0[4], st1[4];
        #pragma unroll
        for (int ni = 0; ni < 4; ++ni) { st0[ni] = f32x4{0.f,0.f,0.f,0.f}; st1[ni] = f32x4{0.f,0.f,0.f,0.f}; }
        {
            bf16x8 kb[4];
            #pragma unroll
            for (int ni = 0; ni < 4; ++ni)
                kb[ni] = *(const bf16x8*)&Ks[cur][(ni * 16 + l15) * 64 + swz0];
            __builtin_amdgcn_s_setprio(1);
            #pragma unroll
            for (int ni = 0; ni < 4; ++ni) {
                st0[ni] = __builtin_amdgcn_mfma_f32_16x16x32_bf16(kb[ni], qf[0][0], st0[ni], 0, 0, 0);
                st1[ni] = __builtin_amdgcn_mfma_f32_16x16x32_bf16(kb[ni], qf[1][0], st1[ni], 0, 0, 0);
            }
            __builtin_amdgcn_s_setprio(0);
            #pragma unroll
            for (int ni = 0; ni < 4; ++ni)
                kb[ni] = *(const bf16x8*)&Ks[cur][(ni * 16 + l15) * 64 + swz1];
            __builtin_amdgcn_s_setprio(1);
            #pragma unroll
            for (int ni = 0; ni < 4; ++ni) {
                st0[ni] = __builtin_amdgcn_mfma_f32_16x16x32_bf16(kb[ni], qf[0][1], st0[ni], 0, 0, 0);
                st1[ni] = __builtin_amdgcn_mfma_f32_16x16x32_bf16(kb[ni], qf[1][1], st1[ni], 0, 0, 0);
            }
            __builtin_amdgcn_s_setprio(0);
        }

        // softmax numerator -> P (bf16) for both groups
        {
            const unsigned long long mq0 = mw0 >> (quad * 4);
            const unsigned long long mq1 = mw1 >> (quad * 4);
            #pragma unroll
            for (int ni = 0; ni < 4; ++ni) {
                unsigned int b4 = (unsigned int)(mq0 >> (ni * 16)) & 0xFu;
                float p0 = (b4 & 1u) ? fast_exp2(st0[ni][0]) : 1.0f;
                float p1 = (b4 & 2u) ? fast_exp2(st0[ni][1]) : 1.0f;
                float p2 = (b4 & 4u) ? fast_exp2(st0[ni][2]) : 1.0f;
                float p3 = (b4 & 8u) ? fast_exp2(st0[ni][3]) : 1.0f;
                *(uint2*)&Ps[w][0][wadr[ni]] = make_uint2(cvt_pk_bf16(p0, p1), cvt_pk_bf16(p2, p3));
                b4 = (unsigned int)(mq1 >> (ni * 16)) & 0xFu;
                p0 = (b4 & 1u) ? fast_exp2(st1[ni][0]) : 1.0f;
                p1 = (b4 & 2u) ? fast_exp2(st1[ni][1]) : 1.0f;
                p2 = (b4 & 4u) ? fast_exp2(st1[ni][2]) : 1.0f;
                p3 = (b4 & 8u) ? fast_exp2(st1[ni][3]) : 1.0f;
                *(uint2*)&Ps[w][1][wadr[ni]] = make_uint2(cvt_pk_bf16(p0, p1), cvt_pk_bf16(p2, p3));
            }
        }

        // PV + row-sum; V fragments loaded once per half, used by both groups
        {
            bf16x8 vb[4];
            #pragma unroll
            for (int nd = 0; nd < 4; ++nd)
                vb[nd] = *(const bf16x8*)&Vs[cur][(nd * 16 + l15) * 64 + swz0];
            bf16x8 pa0 = *(const bf16x8*)&Ps[w][0][padr0];
            bf16x8 pa1 = *(const bf16x8*)&Ps[w][1][padr0];
            __builtin_amdgcn_s_setprio(1);
            l_acc[0] = __builtin_amdgcn_mfma_f32_16x16x32_bf16(pa0, onesf, l_acc[0], 0, 0, 0);
            l_acc[1] = __builtin_amdgcn_mfma_f32_16x16x32_bf16(pa1, onesf, l_acc[1], 0, 0, 0);
            #pragma unroll
            for (int nd = 0; nd < 4; ++nd) {
                o_acc[0][nd] = __builtin_amdgcn_mfma_f32_16x16x32_bf16(pa0, vb[nd], o_acc[0][nd], 0, 0, 0);
                o_acc[1][nd] = __builtin_amdgcn_mfma_f32_16x16x32_bf16(pa1, vb[nd], o_acc[1][nd], 0, 0, 0);
            }
            __builtin_amdgcn_s_setprio(0);

            #pragma unroll
            for (int nd = 0; nd < 4; ++nd)
                vb[nd] = *(const bf16x8*)&Vs[cur][(nd * 16 + l15) * 64 + swz1];
            pa0 = *(const bf16x8*)&Ps[w][0][padr1];
            pa1 = *(const bf16x8*)&Ps[w][1][padr1];
            __builtin_amdgcn_s_setprio(1);
            l_acc[0] = __builtin_amdgcn_mfma_f32_16x16x32_bf16(pa0, onesf, l_acc[0], 0, 0, 0);
            l_acc[1] = __builtin_amdgcn_mfma_f32_16x16x32_bf16(pa1, onesf, l_acc[1], 0, 0, 0);
            #pragma unroll
            for (int nd = 0; nd < 4; ++nd) {
                o_acc[0][nd] = __builtin_amdgcn_mfma_f32_16x16x32_bf16(pa0, vb[nd], o_acc[0][nd], 0, 0, 0);
                o_acc[1][nd] = __builtin_amdgcn_mfma_f32_16x16x32_bf16(pa1, vb[nd], o_acc[1][nd], 0, 0, 0);
            }
            __builtin_amdgcn_s_setprio(0);
        }

        mw0 = mw0n; mw1 = mw1n;
        __syncthreads();   // reads of cur done; prefetch (vmcnt) drained
    }

    // epilogue: lane holds rows g*16 + quad*4 + r, col d = nd*16 + l15
    #pragma unroll
    for (int g = 0; g < 2; ++g) {
        #pragma unroll
        for (int r = 0; r < 4; ++r) {
            float rinv = 1.0f / l_acc[g][r];
            int row = q0 + w * 32 + g * 16 + quad * 4 + r;
            #pragma unroll
            for (int nd = 0; nd < 4; ++nd)
                Om[((size_t)b * SEQ + row) * HID + h * DKK + nd * 16 + l15] =
                    f32_bf16(o_acc[g][nd][r] * rinv);
        }
    }
}

// ---------------------------------------------------------------------------
// Kernel 3: out = Om @ Wo^T + bo (fp32 out).  128x64 tiles, round-4 verified
// double-buffer single-barrier K-loop.
// ---------------------------------------------------------------------------
__global__ __launch_bounds__(256, 2)
void outproj_kernel(const unsigned short* __restrict__ Om, const unsigned short* __restrict__ Wob,
                    const float* __restrict__ bo_, float* __restrict__ out)
{
    const int m0 = blockIdx.x * 128;
    const int n0 = blockIdx.y * 64;
    const int tid  = threadIdx.x;
    const int lane = tid & 63, wid = tid >> 6;
    const int wm = (wid >> 1) * 64, wn = (wid & 1) * 32;
    const int l15 = lane & 15, quad = lane >> 4;

    __shared__ __align__(16) unsigned short As[2][128 * 32];   // 2 x 8 KB
    __shared__ __align__(16) unsigned short Bs[2][64 * 32];    // 2 x 4 KB

    const int r0 = tid >> 2, cg = tid & 3;
    const unsigned short* gA = Om + (size_t)(m0 + r0) * HID + ((cg ^ (r0 & 3)) * 8);
    const unsigned short* gB = Wob + (size_t)(n0 + r0) * HID + ((cg ^ (r0 & 3)) * 8);
    const int cgsel = (quad ^ (l15 & 3)) * 8;

    f32x4 acc[4][2];
    #pragma unroll
    for (int i = 0; i < 4; ++i)
        #pragma unroll
        for (int j = 0; j < 2; ++j)
            acc[i][j] = f32x4{0.f, 0.f, 0.f, 0.f};

    // prologue: stage k0=0
    glds16(gA, &As[0][tid * 8]);
    glds16(gA + (size_t)64 * HID, &As[0][(tid + 256) * 8]);
    glds16(gB, &Bs[0][tid * 8]);
    __syncthreads();

    for (int k0 = 0; k0 < HID; k0 += 32) {
        const int cur = (k0 >> 5) & 1;
        if (k0 + 32 < HID) {
            const int nb = cur ^ 1;
            glds16(gA + k0 + 32, &As[nb][tid * 8]);
            glds16(gA + (size_t)64 * HID + k0 + 32, &As[nb][(tid + 256) * 8]);
            glds16(gB + k0 + 32, &Bs[nb][tid * 8]);
        }

        bf16x8 af[4], bfr[2];
        #pragma unroll
        for (int mi = 0; mi < 4; ++mi)
            af[mi] = *(const bf16x8*)&As[cur][(wm + mi * 16 + l15) * 32 + cgsel];
        #pragma unroll
        for (int ni = 0; ni < 2; ++ni)
            bfr[ni] = *(const bf16x8*)&Bs[cur][(wn + ni * 16 + l15) * 32 + cgsel];
        __builtin_amdgcn_s_setprio(1);
        #pragma unroll
        for (int mi = 0; mi < 4; ++mi)
            #pragma unroll
            for (int ni = 0; ni < 2; ++ni)
                acc[mi][ni] = __builtin_amdgcn_mfma_f32_16x16x32_bf16(
                    af[mi], bfr[ni], acc[mi][ni], 0, 0, 0);
        __builtin_amdgcn_s_setprio(0);
        __syncthreads();
    }

    #pragma unroll
    for (int mi = 0; mi < 4; ++mi) {
        #pragma unroll
        for (int ni = 0; ni < 2; ++ni) {
            int n = n0 + wn + ni * 16 + l15;
            float bv = bo_[n];
            #pragma unroll
            for (int r = 0; r < 4; ++r) {
                int m = m0 + wm + mi * 16 + quad * 4 + r;
                out[(size_t)m * HID + n] = acc[mi][ni][r] + bv;
            }
        }
    }
}

// ---------------------------------------------------------------------------
extern "C" void kernel_launch(void* const* d_in, const int* in_sizes, int n_in,
                              void* d_out, int out_size, void* d_ws, size_t ws_size,
                              hipStream_t stream) {
    const float* q    = (const float*)d_in[0];
    const float* k    = (const float*)d_in[1];
    const float* v    = (const float*)d_in[2];
    const int*   mask = (const int*)  d_in[3];
    const float* Wq   = (const float*)d_in[4];
    const float* bq   = (const float*)d_in[5];
    const float* Wk   = (const float*)d_in[6];
    const float* bk   = (const float*)d_in[7];
    const float* Wv   = (const float*)d_in[8];
    const float* bv   = (const float*)d_in[9];
    const float* Wo   = (const float*)d_in[10];
    const float* bo   = (const float*)d_in[11];
    float* out = (float*)d_out;

    // workspace layout (bf16 element offsets):
    unsigned short* ws  = (unsigned short*)d_ws;
    unsigned short* qb  = ws;                  // 4194304 elems (B*S*H)
    unsigned short* kbx = ws + 4194304;
    unsigned short* vbx = ws + 8388608;
    unsigned short* Wqb = ws + 12582912;       // 1048576 elems each
    unsigned short* Wkb = ws + 13631488;
    unsigned short* Wvb = ws + 14680064;
    unsigned short* Wob = ws + 15728640;
    unsigned short* Qh  = ws + 16777216;
    unsigned short* Kh  = ws + 20971520;
    unsigned short* Vt  = ws + 25165824;
    unsigned short* Om  = ws;                  // alias qb (dead after proj)
    unsigned long long* Mb = (unsigned long long*)(ws + 29360128);  // 1 MB
    unsigned short* Vh  = (unsigned short*)d_out;  // scratch: out dead until outproj

    prep_kernel<<<dim3(16896), 256, 0, stream>>>(q, k, v, Wq, Wk, Wv, Wo, mask, ws, Mb);

    proj_kernel<<<dim3(32, 8, 3), 256, 0, stream>>>(qb, kbx, vbx, Wqb, Wkb, Wvb,
                                                    bq, bk, bv, Qh, Kh, Vh);
    vtrans_kernel<<<dim3(32, 32), 256, 0, stream>>>(Vh, Vt);
    attn_kernel<<<dim3(16, NHEAD, 2), 256, 0, stream>>>(Qh, Kh, Vt, Mb, Om);
    outproj_kernel<<<dim3(32, 16), 256, 0, stream>>>(Om, Wob, bo, out);
}

// Round 7
// 290.749 us; speedup vs baseline: 1.0369x; 1.0369x over previous
//
#include <hip/hip_runtime.h>

#define SEQ   2048
#define NHEAD 16
#define DKK   64
#define HID   1024

typedef __attribute__((ext_vector_type(8))) short bf16x8;
typedef __attribute__((ext_vector_type(4))) float f32x4;

__device__ __forceinline__ unsigned short f32_bf16(float f) {
    unsigned int u = __builtin_bit_cast(unsigned int, f);
    u += 0x7fffu + ((u >> 16) & 1u);
    return (unsigned short)(u >> 16);
}

// one-instruction packed f32x2 -> bf16x2 (RNE), per T12 recipe
__device__ __forceinline__ unsigned int cvt_pk_bf16(float lo, float hi) {
    unsigned int r;
    asm("v_cvt_pk_bf16_f32 %0, %1, %2" : "=v"(r) : "v"(lo), "v"(hi));
    return r;
}

// raw v_exp_f32 (2^x). Scores bounded (|x| < ~45), no range reduction needed.
__device__ __forceinline__ float fast_exp2(float x) {
    float r;
    asm("v_exp_f32 %0, %1" : "=v"(r) : "v"(x));
    return r;
}

// async global->LDS 16B copy (DMA, no VGPR round-trip)
__device__ __forceinline__ void glds16(const void* g, void* l) {
    __builtin_amdgcn_global_load_lds(
        (const __attribute__((address_space(1))) unsigned int*)g,
        (__attribute__((address_space(3))) unsigned int*)l, 16, 0, 0);
}

// ---------------------------------------------------------------------------
// Kernel A: fused prep — fp32->bf16 convert of all 7 tensors + mask bit-pack
// via wave ballot (coalesced lane reads; __ballot IS the packed word).
// ---------------------------------------------------------------------------
__global__ __launch_bounds__(256)
void prep_kernel(const float* __restrict__ q, const float* __restrict__ k,
                 const float* __restrict__ v,
                 const float* __restrict__ Wq, const float* __restrict__ Wk,
                 const float* __restrict__ Wv, const float* __restrict__ Wo,
                 const int* __restrict__ mask,
                 unsigned short* __restrict__ ws, unsigned long long* __restrict__ Mb)
{
    const int bid = blockIdx.x;
    if (bid < 16384) {
        int i = bid * 256 + threadIdx.x;            // float4 index
        const float* src; int off;
        if (i < 1048576)      { src = q;  off = i; }
        else if (i < 2097152) { src = k;  off = i - 1048576; }
        else if (i < 3145728) { src = v;  off = i - 2097152; }
        else if (i < 3407872) { src = Wq; off = i - 3145728; }
        else if (i < 3670016) { src = Wk; off = i - 3407872; }
        else if (i < 3932160) { src = Wv; off = i - 3670016; }
        else                  { src = Wo; off = i - 3932160; }
        float4 a = ((const float4*)src)[off];
        ((uint2*)ws)[i] = make_uint2(cvt_pk_bf16(a.x, a.y), cvt_pk_bf16(a.z, a.w));
    } else {
        // wave g packs 64 words; word j from 64 coalesced ints via ballot
        const int g    = (bid - 16384) * 4 + (threadIdx.x >> 6);   // 0..2047
        const int lane = threadIdx.x & 63;
        const int* src = mask + (size_t)g * 4096;
        unsigned long long* dstw = Mb + (size_t)g * 64;
        #pragma unroll 4
        for (int j = 0; j < 64; ++j) {
            int m = src[j * 64 + lane];
            unsigned long long wv = __ballot(m != 0);
            if (lane == 0) dstw[j] = wv;
        }
    }
}

// ---------------------------------------------------------------------------
// Kernel 1: QKV projections (round-4 verified form: double-buffered LDS,
// one __syncthreads per K-step).  Q pre-scaled by 0.125*log2(e).  z=2 (V)
// writes coalesced [b,h,s,d] into scratch Vh; vtrans builds Vt[d][s].
// ---------------------------------------------------------------------------
__global__ __launch_bounds__(256, 2)
void proj_kernel(const unsigned short* __restrict__ xq, const unsigned short* __restrict__ xk,
                 const unsigned short* __restrict__ xv,
                 const unsigned short* __restrict__ Wqb, const unsigned short* __restrict__ Wkb,
                 const unsigned short* __restrict__ Wvb,
                 const float* __restrict__ bq_, const float* __restrict__ bk_,
                 const float* __restrict__ bv_,
                 unsigned short* __restrict__ Qh, unsigned short* __restrict__ Kh,
                 unsigned short* __restrict__ Vh)
{
    const int z = blockIdx.z;
    const unsigned short* X; const unsigned short* W; const float* bias;
    if (z == 0)      { X = xq; W = Wqb; bias = bq_; }
    else if (z == 1) { X = xk; W = Wkb; bias = bk_; }
    else             { X = xv; W = Wvb; bias = bv_; }

    const int m0 = blockIdx.x * 128;
    const int n0 = blockIdx.y * 128;
    const int tid  = threadIdx.x;
    const int lane = tid & 63, wid = tid >> 6;
    const int wm = (wid >> 1) * 64, wn = (wid & 1) * 64;
    const int l15 = lane & 15, quad = lane >> 4;

    __shared__ __align__(16) unsigned short As[2][128 * 32];   // 2 x 8 KB
    __shared__ __align__(16) unsigned short Bs[2][128 * 32];

    const int r0 = tid >> 2, cg = tid & 3;
    const unsigned short* gA = X + (size_t)(m0 + r0) * HID + ((cg ^ (r0 & 3)) * 8);
    const unsigned short* gB = W + (size_t)(n0 + r0) * HID + ((cg ^ (r0 & 3)) * 8);

    const int cgsel = (quad ^ (l15 & 3)) * 8;

    f32x4 acc[4][4];
    #pragma unroll
    for (int i = 0; i < 4; ++i)
        #pragma unroll
        for (int j = 0; j < 4; ++j)
            acc[i][j] = f32x4{0.f, 0.f, 0.f, 0.f};

    // prologue: stage k0=0 into buf 0
    glds16(gA, &As[0][tid * 8]);
    glds16(gA + (size_t)64 * HID, &As[0][(tid + 256) * 8]);
    glds16(gB, &Bs[0][tid * 8]);
    glds16(gB + (size_t)64 * HID, &Bs[0][(tid + 256) * 8]);
    __syncthreads();

    for (int k0 = 0; k0 < HID; k0 += 32) {
        const int cur = (k0 >> 5) & 1;
        if (k0 + 32 < HID) {                       // prefetch next K-step
            const int nb = cur ^ 1;
            glds16(gA + k0 + 32, &As[nb][tid * 8]);
            glds16(gA + (size_t)64 * HID + k0 + 32, &As[nb][(tid + 256) * 8]);
            glds16(gB + k0 + 32, &Bs[nb][tid * 8]);
            glds16(gB + (size_t)64 * HID + k0 + 32, &Bs[nb][(tid + 256) * 8]);
        }

        bf16x8 af[4], bfr[4];
        #pragma unroll
        for (int mi = 0; mi < 4; ++mi)
            af[mi] = *(const bf16x8*)&As[cur][(wm + mi * 16 + l15) * 32 + cgsel];
        #pragma unroll
        for (int ni = 0; ni < 4; ++ni)
            bfr[ni] = *(const bf16x8*)&Bs[cur][(wn + ni * 16 + l15) * 32 + cgsel];
        __builtin_amdgcn_s_setprio(1);
        #pragma unroll
        for (int mi = 0; mi < 4; ++mi)
            #pragma unroll
            for (int ni = 0; ni < 4; ++ni)
                acc[mi][ni] = __builtin_amdgcn_mfma_f32_16x16x32_bf16(
                    af[mi], bfr[ni], acc[mi][ni], 0, 0, 0);
        __builtin_amdgcn_s_setprio(0);
        __syncthreads();                           // reads done + prefetch drained
    }

    const float QSCALE = 0.18033688f;   // 0.125 * log2(e)
    #pragma unroll
    for (int mi = 0; mi < 4; ++mi) {
        #pragma unroll
        for (int ni = 0; ni < 4; ++ni) {
            int n = n0 + wn + ni * 16 + l15;
            float bv = bias[n];
            int hh = n >> 6, d = n & 63;
            #pragma unroll
            for (int r = 0; r < 4; ++r) {
                int m = m0 + wm + mi * 16 + quad * 4 + r;
                int bb = m >> 11, s = m & 2047;
                float val = acc[mi][ni][r] + bv;
                if (z == 0)
                    Qh[((size_t)(bb * NHEAD + hh) * SEQ + s) * DKK + d] = f32_bf16(val * QSCALE);
                else if (z == 1)
                    Kh[((size_t)(bb * NHEAD + hh) * SEQ + s) * DKK + d] = f32_bf16(val);
                else
                    Vh[((size_t)(bb * NHEAD + hh) * SEQ + s) * DKK + d] = f32_bf16(val);
            }
        }
    }
}

// ---------------------------------------------------------------------------
// Kernel 1b: Vh[b,h,s,d] -> Vt[b,h,d,s] transpose (round-4 verified).
// ---------------------------------------------------------------------------
__global__ __launch_bounds__(256)
void vtrans_kernel(const unsigned short* __restrict__ Vh, unsigned short* __restrict__ Vt)
{
    __shared__ unsigned int T[64 * 32];
    const int bh = blockIdx.y;
    const int s0 = blockIdx.x * 64;
    const int tid = threadIdx.x;
    const unsigned short* src = Vh + ((size_t)bh * SEQ + s0) * DKK;
    unsigned short* dst = Vt + (size_t)bh * DKK * SEQ + s0;

    #pragma unroll
    for (int j = 0; j < 2; ++j) {
        int i = tid + j * 256;
        int s = i >> 3, ch = i & 7;                // 16B chunk: d = ch*8..+7
        uint4 d4 = *(const uint4*)(src + (size_t)s * DKK + ch * 8);
        *(uint4*)&T[s * 32 + 4 * (ch ^ (s >> 3))] = d4;
    }
    __syncthreads();
    #pragma unroll
    for (int j = 0; j < 2; ++j) {
        int i = tid + j * 256;
        int d = i >> 3, sb = (i & 7) * 8;          // 8 consecutive s at row d
        int d2 = d >> 1, hi = d & 1;
        int g = d2 >> 2, w4 = d2 & 3;
        unsigned int r[8];
        #pragma unroll
        for (int kk = 0; kk < 8; ++kk) {
            int s = sb + kk;
            r[kk] = T[s * 32 + 4 * (g ^ (s >> 3)) + w4];
        }
        uint4 ov;
        if (hi) {
            ov.x = (r[0] >> 16) | (r[1] & 0xffff0000u);
            ov.y = (r[2] >> 16) | (r[3] & 0xffff0000u);
            ov.z = (r[4] >> 16) | (r[5] & 0xffff0000u);
            ov.w = (r[6] >> 16) | (r[7] & 0xffff0000u);
        } else {
            ov.x = (r[0] & 0xffffu) | (r[1] << 16);
            ov.y = (r[2] & 0xffffu) | (r[3] << 16);
            ov.z = (r[4] & 0xffffu) | (r[5] << 16);
            ov.w = (r[6] & 0xffffu) | (r[7] << 16);
        }
        *(uint4*)(dst + (size_t)d * SEQ + sb) = ov;
    }
}

// ---------------------------------------------------------------------------
// Kernel 2: flash attention, swapped-QK^T, QBLK=64 (round-4 geometry) with
// counted-vmcnt pipeline (T4):
//   A: issue batch kt+1 (4 DMA + 1 mask word = exactly 5 vm ops)
//   B: s_waitcnt vmcnt(5)  -> waits ONLY batch kt (issued a full iter ago,
//      latency already hidden under iter kt-1's compute) ; raw s_barrier
//   C: ds_read + QK^T + softmax + PV          (no sched pinning inside)
//   D: raw s_barrier (reads of cur done before next A overwrites)
// vs round 4's __syncthreads which drained the JUST-issued prefetch
// (vmcnt(0)) and exposed ~250 cyc/tile.
// LDS = 2*8K (K) + 2*8K (V) + 4*2K (P) = 40960 B -> 4 blocks/CU.
// ---------------------------------------------------------------------------
__global__ __launch_bounds__(256, 4)
void attn_kernel(const unsigned short* __restrict__ Qh, const unsigned short* __restrict__ Kh,
                 const unsigned short* __restrict__ Vt,
                 const unsigned long long* __restrict__ Mb,
                 unsigned short* __restrict__ Om)
{
    const int qt = blockIdx.x;       // 0..31
    const int h  = blockIdx.y;
    const int b  = blockIdx.z;
    const int tid  = threadIdx.x;
    const int lane = tid & 63, w = tid >> 6;
    const int l15 = lane & 15, quad = lane >> 4;
    const int q0 = qt * 64;

    const size_t hoff = (size_t)(b * NHEAD + h) * SEQ * DKK;
    const unsigned short* Qp = Qh + hoff;
    const unsigned short* Kp = Kh + hoff;
    const unsigned short* Vp = Vt + hoff;   // [d][s]

    __shared__ __align__(16) unsigned short Ks[2][64 * 64];
    __shared__ __align__(16) unsigned short Vs[2][64 * 64];
    __shared__ __align__(16) unsigned short Ps[4][16 * 64];

    const int sr0 = tid >> 3, ss0 = tid & 7;
    const int sr1 = sr0 + 32;
    const unsigned short* Kg0 = Kp + sr0 * DKK + ((ss0 ^ (sr0 & 7)) * 8);
    const unsigned short* Kg1 = Kp + sr1 * DKK + ((ss0 ^ (sr1 & 7)) * 8);
    const unsigned short* Vg0 = Vp + (size_t)sr0 * SEQ + ((ss0 ^ (sr0 & 7)) * 8);
    const unsigned short* Vg1 = Vp + (size_t)sr1 * SEQ + ((ss0 ^ (sr1 & 7)) * 8);

    const int swz0 = ((0 * 4 + quad) ^ (l15 & 7)) * 8;
    const int swz1 = ((1 * 4 + quad) ^ (l15 & 7)) * 8;

    const int xsw = l15 & 14;
    int wadr[4];
    #pragma unroll
    for (int ni = 0; ni < 4; ++ni)
        wadr[ni] = l15 * 64 + (((ni * 4 + quad) ^ xsw) * 4);
    const int padr0 = l15 * 64 + (((quad * 2) ^ xsw) * 4);
    const int padr1 = l15 * 64 + (((8 + quad * 2) ^ xsw) * 4);

    // prologue: issue tile 0 (4 DMA); Q frags + mask word ride the same queue
    glds16(Kg0, &Ks[0][tid * 8]);
    glds16(Kg1, &Ks[0][2048 + tid * 8]);
    glds16(Vg0, &Vs[0][tid * 8]);
    glds16(Vg1, &Vs[0][2048 + tid * 8]);

    bf16x8 qf[2];
    #pragma unroll
    for (int kc = 0; kc < 2; ++kc)
        qf[kc] = *(const bf16x8*)(Qp + (size_t)(q0 + w * 16 + l15) * DKK + kc * 32 + quad * 8);

    bf16x8 onesf;
    #pragma unroll
    for (int i = 0; i < 8; ++i) onesf[i] = (short)0x3F80;

    f32x4 o_acc[4];
    f32x4 l_acc = f32x4{0.f, 0.f, 0.f, 0.f};
    #pragma unroll
    for (int nd = 0; nd < 4; ++nd) o_acc[nd] = f32x4{0.f, 0.f, 0.f, 0.f};

    const unsigned long long* Mrow =
        Mb + ((size_t)b * SEQ + q0 + w * 16 + l15) * (SEQ / 64);
    unsigned long long mw_cur = Mrow[0];

    for (int kt = 0; kt < SEQ / 64; ++kt) {
        const int cur = kt & 1;
        unsigned long long mw_nxt = 0ull;

        // --- A: issue next batch (exactly 5 vm ops when taken) ------------
        if (kt < SEQ / 64 - 1) {
            const int nb = cur ^ 1;
            glds16(Kg0 + (kt + 1) * 64 * DKK, &Ks[nb][tid * 8]);
            glds16(Kg1 + (kt + 1) * 64 * DKK, &Ks[nb][2048 + tid * 8]);
            glds16(Vg0 + (kt + 1) * 64,       &Vs[nb][tid * 8]);
            glds16(Vg1 + (kt + 1) * 64,       &Vs[nb][2048 + tid * 8]);
            mw_nxt = Mrow[kt + 1];
            // --- B: wait only batch kt (all but the 5 newest), then join --
            asm volatile("s_waitcnt vmcnt(5)" ::: "memory");
        } else {
            asm volatile("s_waitcnt vmcnt(0)" ::: "memory");
        }
        __builtin_amdgcn_s_barrier();          // batch kt resident for ALL waves
        __builtin_amdgcn_sched_barrier(0);     // keep C below the barrier

        // --- C: compute on tile kt ----------------------------------------
        const unsigned long long mwq = mw_cur >> (quad * 4);

        f32x4 st[4];
        #pragma unroll
        for (int ni = 0; ni < 4; ++ni) st[ni] = f32x4{0.f, 0.f, 0.f, 0.f};
        {
            bf16x8 kb[4];
            #pragma unroll
            for (int ni = 0; ni < 4; ++ni)
                kb[ni] = *(const bf16x8*)&Ks[cur][(ni * 16 + l15) * 64 + swz0];
            __builtin_amdgcn_s_setprio(1);
            #pragma unroll
            for (int ni = 0; ni < 4; ++ni)
                st[ni] = __builtin_amdgcn_mfma_f32_16x16x32_bf16(kb[ni], qf[0], st[ni], 0, 0, 0);
            __builtin_amdgcn_s_setprio(0);
            #pragma unroll
            for (int ni = 0; ni < 4; ++ni)
                kb[ni] = *(const bf16x8*)&Ks[cur][(ni * 16 + l15) * 64 + swz1];
            __builtin_amdgcn_s_setprio(1);
            #pragma unroll
            for (int ni = 0; ni < 4; ++ni)
                st[ni] = __builtin_amdgcn_mfma_f32_16x16x32_bf16(kb[ni], qf[1], st[ni], 0, 0, 0);
            __builtin_amdgcn_s_setprio(0);
        }

        // softmax numerator -> P (bf16), packed via v_cvt_pk_bf16_f32
        #pragma unroll
        for (int ni = 0; ni < 4; ++ni) {
            const unsigned int b4 = (unsigned int)(mwq >> (ni * 16)) & 0xFu;
            float p0 = (b4 & 1u) ? fast_exp2(st[ni][0]) : 1.0f;
            float p1 = (b4 & 2u) ? fast_exp2(st[ni][1]) : 1.0f;
            float p2 = (b4 & 4u) ? fast_exp2(st[ni][2]) : 1.0f;
            float p3 = (b4 & 8u) ? fast_exp2(st[ni][3]) : 1.0f;
            *(uint2*)&Ps[w][wadr[ni]] = make_uint2(cvt_pk_bf16(p0, p1), cvt_pk_bf16(p2, p3));
        }

        // PV + row-sum (ones trick)
        {
            bf16x8 pa = *(const bf16x8*)&Ps[w][padr0];
            bf16x8 vb[4];
            #pragma unroll
            for (int nd = 0; nd < 4; ++nd)
                vb[nd] = *(const bf16x8*)&Vs[cur][(nd * 16 + l15) * 64 + swz0];
            __builtin_amdgcn_s_setprio(1);
            l_acc = __builtin_amdgcn_mfma_f32_16x16x32_bf16(pa, onesf, l_acc, 0, 0, 0);
            #pragma unroll
            for (int nd = 0; nd < 4; ++nd)
                o_acc[nd] = __builtin_amdgcn_mfma_f32_16x16x32_bf16(pa, vb[nd], o_acc[nd], 0, 0, 0);
            __builtin_amdgcn_s_setprio(0);

            pa = *(const bf16x8*)&Ps[w][padr1];
            #pragma unroll
            for (int nd = 0; nd < 4; ++nd)
                vb[nd] = *(const bf16x8*)&Vs[cur][(nd * 16 + l15) * 64 + swz1];
            __builtin_amdgcn_s_setprio(1);
            l_acc = __builtin_amdgcn_mfma_f32_16x16x32_bf16(pa, onesf, l_acc, 0, 0, 0);
            #pragma unroll
            for (int nd = 0; nd < 4; ++nd)
                o_acc[nd] = __builtin_amdgcn_mfma_f32_16x16x32_bf16(pa, vb[nd], o_acc[nd], 0, 0, 0);
            __builtin_amdgcn_s_setprio(0);
        }

        mw_cur = mw_nxt;

        // --- D: all reads of buf[cur] done before next A overwrites it ----
        __builtin_amdgcn_s_barrier();
        __builtin_amdgcn_sched_barrier(0);     // pin next A below this barrier
    }

    #pragma unroll
    for (int r = 0; r < 4; ++r) {
        float rinv = 1.0f / l_acc[r];
        int row = q0 + w * 16 + quad * 4 + r;
        #pragma unroll
        for (int nd = 0; nd < 4; ++nd)
            Om[((size_t)b * SEQ + row) * HID + h * DKK + nd * 16 + l15] =
                f32_bf16(o_acc[nd][r] * rinv);
    }
}

// ---------------------------------------------------------------------------
// Kernel 3: out = Om @ Wo^T + bo (fp32 out).  128x64 tiles, round-4 verified
// double-buffer single-barrier K-loop.
// ---------------------------------------------------------------------------
__global__ __launch_bounds__(256, 2)
void outproj_kernel(const unsigned short* __restrict__ Om, const unsigned short* __restrict__ Wob,
                    const float* __restrict__ bo_, float* __restrict__ out)
{
    const int m0 = blockIdx.x * 128;
    const int n0 = blockIdx.y * 64;
    const int tid  = threadIdx.x;
    const int lane = tid & 63, wid = tid >> 6;
    const int wm = (wid >> 1) * 64, wn = (wid & 1) * 32;
    const int l15 = lane & 15, quad = lane >> 4;

    __shared__ __align__(16) unsigned short As[2][128 * 32];   // 2 x 8 KB
    __shared__ __align__(16) unsigned short Bs[2][64 * 32];    // 2 x 4 KB

    const int r0 = tid >> 2, cg = tid & 3;
    const unsigned short* gA = Om + (size_t)(m0 + r0) * HID + ((cg ^ (r0 & 3)) * 8);
    const unsigned short* gB = Wob + (size_t)(n0 + r0) * HID + ((cg ^ (r0 & 3)) * 8);
    const int cgsel = (quad ^ (l15 & 3)) * 8;

    f32x4 acc[4][2];
    #pragma unroll
    for (int i = 0; i < 4; ++i)
        #pragma unroll
        for (int j = 0; j < 2; ++j)
            acc[i][j] = f32x4{0.f, 0.f, 0.f, 0.f};

    // prologue: stage k0=0
    glds16(gA, &As[0][tid * 8]);
    glds16(gA + (size_t)64 * HID, &As[0][(tid + 256) * 8]);
    glds16(gB, &Bs[0][tid * 8]);
    __syncthreads();

    for (int k0 = 0; k0 < HID; k0 += 32) {
        const int cur = (k0 >> 5) & 1;
        if (k0 + 32 < HID) {
            const int nb = cur ^ 1;
            glds16(gA + k0 + 32, &As[nb][tid * 8]);
            glds16(gA + (size_t)64 * HID + k0 + 32, &As[nb][(tid + 256) * 8]);
            glds16(gB + k0 + 32, &Bs[nb][tid * 8]);
        }

        bf16x8 af[4], bfr[2];
        #pragma unroll
        for (int mi = 0; mi < 4; ++mi)
            af[mi] = *(const bf16x8*)&As[cur][(wm + mi * 16 + l15) * 32 + cgsel];
        #pragma unroll
        for (int ni = 0; ni < 2; ++ni)
            bfr[ni] = *(const bf16x8*)&Bs[cur][(wn + ni * 16 + l15) * 32 + cgsel];
        __builtin_amdgcn_s_setprio(1);
        #pragma unroll
        for (int mi = 0; mi < 4; ++mi)
            #pragma unroll
            for (int ni = 0; ni < 2; ++ni)
                acc[mi][ni] = __builtin_amdgcn_mfma_f32_16x16x32_bf16(
                    af[mi], bfr[ni], acc[mi][ni], 0, 0, 0);
        __builtin_amdgcn_s_setprio(0);
        __syncthreads();
    }

    #pragma unroll
    for (int mi = 0; mi < 4; ++mi) {
        #pragma unroll
        for (int ni = 0; ni < 2; ++ni) {
            int n = n0 + wn + ni * 16 + l15;
            float bv = bo_[n];
            #pragma unroll
            for (int r = 0; r < 4; ++r) {
                int m = m0 + wm + mi * 16 + quad * 4 + r;
                out[(size_t)m * HID + n] = acc[mi][ni][r] + bv;
            }
        }
    }
}

// ---------------------------------------------------------------------------
extern "C" void kernel_launch(void* const* d_in, const int* in_sizes, int n_in,
                              void* d_out, int out_size, void* d_ws, size_t ws_size,
                              hipStream_t stream) {
    const float* q    = (const float*)d_in[0];
    const float* k    = (const float*)d_in[1];
    const float* v    = (const float*)d_in[2];
    const int*   mask = (const int*)  d_in[3];
    const float* Wq   = (const float*)d_in[4];
    const float* bq   = (const float*)d_in[5];
    const float* Wk   = (const float*)d_in[6];
    const float* bk   = (const float*)d_in[7];
    const float* Wv   = (const float*)d_in[8];
    const float* bv   = (const float*)d_in[9];
    const float* Wo   = (const float*)d_in[10];
    const float* bo   = (const float*)d_in[11];
    float* out = (float*)d_out;

    // workspace layout (bf16 element offsets):
    unsigned short* ws  = (unsigned short*)d_ws;
    unsigned short* qb  = ws;                  // 4194304 elems (B*S*H)
    unsigned short* kbx = ws + 4194304;
    unsigned short* vbx = ws + 8388608;
    unsigned short* Wqb = ws + 12582912;       // 1048576 elems each
    unsigned short* Wkb = ws + 13631488;
    unsigned short* Wvb = ws + 14680064;
    unsigned short* Wob = ws + 15728640;
    unsigned short* Qh  = ws + 16777216;
    unsigned short* Kh  = ws + 20971520;
    unsigned short* Vt  = ws + 25165824;
    unsigned short* Om  = ws;                  // alias qb (dead after proj)
    unsigned long long* Mb = (unsigned long long*)(ws + 29360128);  // 1 MB
    unsigned short* Vh  = (unsigned short*)d_out;  // scratch: out dead until outproj

    prep_kernel<<<dim3(16896), 256, 0, stream>>>(q, k, v, Wq, Wk, Wv, Wo, mask, ws, Mb);

    proj_kernel<<<dim3(32, 8, 3), 256, 0, stream>>>(qb, kbx, vbx, Wqb, Wkb, Wvb,
                                                    bq, bk, bv, Qh, Kh, Vh);
    vtrans_kernel<<<dim3(32, 32), 256, 0, stream>>>(Vh, Vt);
    attn_kernel<<<dim3(32, NHEAD, 2), 256, 0, stream>>>(Qh, Kh, Vt, Mb, Om);
    outproj_kernel<<<dim3(32, 16), 256, 0, stream>>>(Om, Wob, bo, out);
}

// Round 8
// 285.769 us; speedup vs baseline: 1.0550x; 1.0174x over previous
//
#include <hip/hip_runtime.h>

#define SEQ   2048
#define NHEAD 16
#define DKK   64
#define HID   1024

typedef __attribute__((ext_vector_type(8))) short bf16x8;
typedef __attribute__((ext_vector_type(4))) float f32x4;

__device__ __forceinline__ unsigned short f32_bf16(float f) {
    unsigned int u = __builtin_bit_cast(unsigned int, f);
    u += 0x7fffu + ((u >> 16) & 1u);
    return (unsigned short)(u >> 16);
}

// one-instruction packed f32x2 -> bf16x2 (RNE), per T12 recipe
__device__ __forceinline__ unsigned int cvt_pk_bf16(float lo, float hi) {
    unsigned int r;
    asm("v_cvt_pk_bf16_f32 %0, %1, %2" : "=v"(r) : "v"(lo), "v"(hi));
    return r;
}

// raw v_exp_f32 (2^x). Scores bounded (|x| < ~45), no range reduction needed.
__device__ __forceinline__ float fast_exp2(float x) {
    float r;
    asm("v_exp_f32 %0, %1" : "=v"(r) : "v"(x));
    return r;
}

// async global->LDS 16B copy (DMA, no VGPR round-trip)
__device__ __forceinline__ void glds16(const void* g, void* l) {
    __builtin_amdgcn_global_load_lds(
        (const __attribute__((address_space(1))) unsigned int*)g,
        (__attribute__((address_space(3))) unsigned int*)l, 16, 0, 0);
}

// ---------------------------------------------------------------------------
// Kernel A: fused prep — fp32->bf16 convert of all 7 tensors + mask bit-pack.
// Mask pack: R4-verified int4 form (16 independent pipelined loads/word).
// The ballot variant (R5/R7) measured ~+11 us: 64 serialized load->ballot
// dependencies per wave.
// ---------------------------------------------------------------------------
__global__ __launch_bounds__(256)
void prep_kernel(const float* __restrict__ q, const float* __restrict__ k,
                 const float* __restrict__ v,
                 const float* __restrict__ Wq, const float* __restrict__ Wk,
                 const float* __restrict__ Wv, const float* __restrict__ Wo,
                 const int* __restrict__ mask,
                 unsigned short* __restrict__ ws, unsigned long long* __restrict__ Mb)
{
    const int bid = blockIdx.x;
    if (bid < 16384) {
        int i = bid * 256 + threadIdx.x;            // float4 index
        const float* src; int off;
        if (i < 1048576)      { src = q;  off = i; }
        else if (i < 2097152) { src = k;  off = i - 1048576; }
        else if (i < 3145728) { src = v;  off = i - 2097152; }
        else if (i < 3407872) { src = Wq; off = i - 3145728; }
        else if (i < 3670016) { src = Wk; off = i - 3407872; }
        else if (i < 3932160) { src = Wv; off = i - 3670016; }
        else                  { src = Wo; off = i - 3932160; }
        float4 a = ((const float4*)src)[off];
        ((uint2*)ws)[i] = make_uint2(cvt_pk_bf16(a.x, a.y), cvt_pk_bf16(a.z, a.w));
    } else {
        int idx = (bid - 16384) * 256 + threadIdx.x;
        const int* src = mask + (size_t)idx * 64;
        unsigned long long wv = 0;
        #pragma unroll
        for (int i = 0; i < 16; ++i) {
            int4 m4 = *(const int4*)(src + i * 4);
            wv |= (unsigned long long)(m4.x != 0) << (i * 4 + 0);
            wv |= (unsigned long long)(m4.y != 0) << (i * 4 + 1);
            wv |= (unsigned long long)(m4.z != 0) << (i * 4 + 2);
            wv |= (unsigned long long)(m4.w != 0) << (i * 4 + 3);
        }
        Mb[idx] = wv;
    }
}

// ---------------------------------------------------------------------------
// Kernel 1: QKV projections (round-4 verified form: double-buffered LDS,
// one __syncthreads per K-step).  Q pre-scaled by 0.125*log2(e).  z=2 (V)
// writes coalesced [b,h,s,d] into scratch Vh; vtrans builds Vt[d][s].
// ---------------------------------------------------------------------------
__global__ __launch_bounds__(256, 2)
void proj_kernel(const unsigned short* __restrict__ xq, const unsigned short* __restrict__ xk,
                 const unsigned short* __restrict__ xv,
                 const unsigned short* __restrict__ Wqb, const unsigned short* __restrict__ Wkb,
                 const unsigned short* __restrict__ Wvb,
                 const float* __restrict__ bq_, const float* __restrict__ bk_,
                 const float* __restrict__ bv_,
                 unsigned short* __restrict__ Qh, unsigned short* __restrict__ Kh,
                 unsigned short* __restrict__ Vh)
{
    const int z = blockIdx.z;
    const unsigned short* X; const unsigned short* W; const float* bias;
    if (z == 0)      { X = xq; W = Wqb; bias = bq_; }
    else if (z == 1) { X = xk; W = Wkb; bias = bk_; }
    else             { X = xv; W = Wvb; bias = bv_; }

    const int m0 = blockIdx.x * 128;
    const int n0 = blockIdx.y * 128;
    const int tid  = threadIdx.x;
    const int lane = tid & 63, wid = tid >> 6;
    const int wm = (wid >> 1) * 64, wn = (wid & 1) * 64;
    const int l15 = lane & 15, quad = lane >> 4;

    __shared__ __align__(16) unsigned short As[2][128 * 32];   // 2 x 8 KB
    __shared__ __align__(16) unsigned short Bs[2][128 * 32];

    const int r0 = tid >> 2, cg = tid & 3;
    const unsigned short* gA = X + (size_t)(m0 + r0) * HID + ((cg ^ (r0 & 3)) * 8);
    const unsigned short* gB = W + (size_t)(n0 + r0) * HID + ((cg ^ (r0 & 3)) * 8);

    const int cgsel = (quad ^ (l15 & 3)) * 8;

    f32x4 acc[4][4];
    #pragma unroll
    for (int i = 0; i < 4; ++i)
        #pragma unroll
        for (int j = 0; j < 4; ++j)
            acc[i][j] = f32x4{0.f, 0.f, 0.f, 0.f};

    // prologue: stage k0=0 into buf 0
    glds16(gA, &As[0][tid * 8]);
    glds16(gA + (size_t)64 * HID, &As[0][(tid + 256) * 8]);
    glds16(gB, &Bs[0][tid * 8]);
    glds16(gB + (size_t)64 * HID, &Bs[0][(tid + 256) * 8]);
    __syncthreads();

    for (int k0 = 0; k0 < HID; k0 += 32) {
        const int cur = (k0 >> 5) & 1;
        if (k0 + 32 < HID) {                       // prefetch next K-step
            const int nb = cur ^ 1;
            glds16(gA + k0 + 32, &As[nb][tid * 8]);
            glds16(gA + (size_t)64 * HID + k0 + 32, &As[nb][(tid + 256) * 8]);
            glds16(gB + k0 + 32, &Bs[nb][tid * 8]);
            glds16(gB + (size_t)64 * HID + k0 + 32, &Bs[nb][(tid + 256) * 8]);
        }

        bf16x8 af[4], bfr[4];
        #pragma unroll
        for (int mi = 0; mi < 4; ++mi)
            af[mi] = *(const bf16x8*)&As[cur][(wm + mi * 16 + l15) * 32 + cgsel];
        #pragma unroll
        for (int ni = 0; ni < 4; ++ni)
            bfr[ni] = *(const bf16x8*)&Bs[cur][(wn + ni * 16 + l15) * 32 + cgsel];
        __builtin_amdgcn_s_setprio(1);
        #pragma unroll
        for (int mi = 0; mi < 4; ++mi)
            #pragma unroll
            for (int ni = 0; ni < 4; ++ni)
                acc[mi][ni] = __builtin_amdgcn_mfma_f32_16x16x32_bf16(
                    af[mi], bfr[ni], acc[mi][ni], 0, 0, 0);
        __builtin_amdgcn_s_setprio(0);
        __syncthreads();                           // reads done + prefetch drained
    }

    const float QSCALE = 0.18033688f;   // 0.125 * log2(e)
    #pragma unroll
    for (int mi = 0; mi < 4; ++mi) {
        #pragma unroll
        for (int ni = 0; ni < 4; ++ni) {
            int n = n0 + wn + ni * 16 + l15;
            float bv = bias[n];
            int hh = n >> 6, d = n & 63;
            #pragma unroll
            for (int r = 0; r < 4; ++r) {
                int m = m0 + wm + mi * 16 + quad * 4 + r;
                int bb = m >> 11, s = m & 2047;
                float val = acc[mi][ni][r] + bv;
                if (z == 0)
                    Qh[((size_t)(bb * NHEAD + hh) * SEQ + s) * DKK + d] = f32_bf16(val * QSCALE);
                else if (z == 1)
                    Kh[((size_t)(bb * NHEAD + hh) * SEQ + s) * DKK + d] = f32_bf16(val);
                else
                    Vh[((size_t)(bb * NHEAD + hh) * SEQ + s) * DKK + d] = f32_bf16(val);
            }
        }
    }
}

// ---------------------------------------------------------------------------
// Kernel 1b: Vh[b,h,s,d] -> Vt[b,h,d,s] transpose (round-4 verified).
// ---------------------------------------------------------------------------
__global__ __launch_bounds__(256)
void vtrans_kernel(const unsigned short* __restrict__ Vh, unsigned short* __restrict__ Vt)
{
    __shared__ unsigned int T[64 * 32];
    const int bh = blockIdx.y;
    const int s0 = blockIdx.x * 64;
    const int tid = threadIdx.x;
    const unsigned short* src = Vh + ((size_t)bh * SEQ + s0) * DKK;
    unsigned short* dst = Vt + (size_t)bh * DKK * SEQ + s0;

    #pragma unroll
    for (int j = 0; j < 2; ++j) {
        int i = tid + j * 256;
        int s = i >> 3, ch = i & 7;                // 16B chunk: d = ch*8..+7
        uint4 d4 = *(const uint4*)(src + (size_t)s * DKK + ch * 8);
        *(uint4*)&T[s * 32 + 4 * (ch ^ (s >> 3))] = d4;
    }
    __syncthreads();
    #pragma unroll
    for (int j = 0; j < 2; ++j) {
        int i = tid + j * 256;
        int d = i >> 3, sb = (i & 7) * 8;          // 8 consecutive s at row d
        int d2 = d >> 1, hi = d & 1;
        int g = d2 >> 2, w4 = d2 & 3;
        unsigned int r[8];
        #pragma unroll
        for (int kk = 0; kk < 8; ++kk) {
            int s = sb + kk;
            r[kk] = T[s * 32 + 4 * (g ^ (s >> 3)) + w4];
        }
        uint4 ov;
        if (hi) {
            ov.x = (r[0] >> 16) | (r[1] & 0xffff0000u);
            ov.y = (r[2] >> 16) | (r[3] & 0xffff0000u);
            ov.z = (r[4] >> 16) | (r[5] & 0xffff0000u);
            ov.w = (r[6] >> 16) | (r[7] & 0xffff0000u);
        } else {
            ov.x = (r[0] & 0xffffu) | (r[1] << 16);
            ov.y = (r[2] & 0xffffu) | (r[3] << 16);
            ov.z = (r[4] & 0xffffu) | (r[5] << 16);
            ov.w = (r[6] & 0xffffu) | (r[7] << 16);
        }
        *(uint4*)(dst + (size_t)d * SEQ + sb) = ov;
    }
}

// ---------------------------------------------------------------------------
// Kernel 2: flash attention (R7-verified pipeline) + XCD-aware block remap.
// All 1024 blocks are co-resident (4/CU); default round-robin puts every
// (b,h) on every XCD -> each private L2 fetches ~the whole 16 MB K/V set
// (FETCH 70 MB vs 25 MB unique).  Remap flat = (hb&7) + 8*(qt + 32*(hb>>3))
// puts all 32 q-tiles of one (b,h) on ONE XCD: per-XCD K/V working set
// 4 x 512 KB = 2 MB -> fits 4 MB L2, K/V fetched once.
// ---------------------------------------------------------------------------
__global__ __launch_bounds__(256, 4)
void attn_kernel(const unsigned short* __restrict__ Qh, const unsigned short* __restrict__ Kh,
                 const unsigned short* __restrict__ Vt,
                 const unsigned long long* __restrict__ Mb,
                 unsigned short* __restrict__ Om)
{
    // XCD-aware decode: flat%8 = XCD (round-robin dispatch, m09/T1)
    const int flat = blockIdx.x;           // 0..1023
    const int xcd  = flat & 7;
    const int rest = flat >> 3;
    const int qt   = rest & 31;
    const int g    = rest >> 5;            // 0..3
    const int hb   = g * 8 + xcd;          // 0..31
    const int h    = hb & 15;
    const int b    = hb >> 4;

    const int tid  = threadIdx.x;
    const int lane = tid & 63, w = tid >> 6;
    const int l15 = lane & 15, quad = lane >> 4;
    const int q0 = qt * 64;

    const size_t hoff = (size_t)(b * NHEAD + h) * SEQ * DKK;
    const unsigned short* Qp = Qh + hoff;
    const unsigned short* Kp = Kh + hoff;
    const unsigned short* Vp = Vt + hoff;   // [d][s]

    __shared__ __align__(16) unsigned short Ks[2][64 * 64];
    __shared__ __align__(16) unsigned short Vs[2][64 * 64];
    __shared__ __align__(16) unsigned short Ps[4][16 * 64];

    const int sr0 = tid >> 3, ss0 = tid & 7;
    const int sr1 = sr0 + 32;
    const unsigned short* Kg0 = Kp + sr0 * DKK + ((ss0 ^ (sr0 & 7)) * 8);
    const unsigned short* Kg1 = Kp + sr1 * DKK + ((ss0 ^ (sr1 & 7)) * 8);
    const unsigned short* Vg0 = Vp + (size_t)sr0 * SEQ + ((ss0 ^ (sr0 & 7)) * 8);
    const unsigned short* Vg1 = Vp + (size_t)sr1 * SEQ + ((ss0 ^ (sr1 & 7)) * 8);

    const int swz0 = ((0 * 4 + quad) ^ (l15 & 7)) * 8;
    const int swz1 = ((1 * 4 + quad) ^ (l15 & 7)) * 8;

    const int xsw = l15 & 14;
    int wadr[4];
    #pragma unroll
    for (int ni = 0; ni < 4; ++ni)
        wadr[ni] = l15 * 64 + (((ni * 4 + quad) ^ xsw) * 4);
    const int padr0 = l15 * 64 + (((quad * 2) ^ xsw) * 4);
    const int padr1 = l15 * 64 + (((8 + quad * 2) ^ xsw) * 4);

    // prologue: issue tile 0 (4 DMA); Q frags + mask word ride the same queue
    glds16(Kg0, &Ks[0][tid * 8]);
    glds16(Kg1, &Ks[0][2048 + tid * 8]);
    glds16(Vg0, &Vs[0][tid * 8]);
    glds16(Vg1, &Vs[0][2048 + tid * 8]);

    bf16x8 qf[2];
    #pragma unroll
    for (int kc = 0; kc < 2; ++kc)
        qf[kc] = *(const bf16x8*)(Qp + (size_t)(q0 + w * 16 + l15) * DKK + kc * 32 + quad * 8);

    bf16x8 onesf;
    #pragma unroll
    for (int i = 0; i < 8; ++i) onesf[i] = (short)0x3F80;

    f32x4 o_acc[4];
    f32x4 l_acc = f32x4{0.f, 0.f, 0.f, 0.f};
    #pragma unroll
    for (int nd = 0; nd < 4; ++nd) o_acc[nd] = f32x4{0.f, 0.f, 0.f, 0.f};

    const unsigned long long* Mrow =
        Mb + ((size_t)b * SEQ + q0 + w * 16 + l15) * (SEQ / 64);
    unsigned long long mw_cur = Mrow[0];

    for (int kt = 0; kt < SEQ / 64; ++kt) {
        const int cur = kt & 1;
        unsigned long long mw_nxt = 0ull;

        // --- A: issue next batch (exactly 5 vm ops when taken) ------------
        if (kt < SEQ / 64 - 1) {
            const int nb = cur ^ 1;
            glds16(Kg0 + (kt + 1) * 64 * DKK, &Ks[nb][tid * 8]);
            glds16(Kg1 + (kt + 1) * 64 * DKK, &Ks[nb][2048 + tid * 8]);
            glds16(Vg0 + (kt + 1) * 64,       &Vs[nb][tid * 8]);
            glds16(Vg1 + (kt + 1) * 64,       &Vs[nb][2048 + tid * 8]);
            mw_nxt = Mrow[kt + 1];
            // --- B: wait only batch kt (all but the 5 newest), then join --
            asm volatile("s_waitcnt vmcnt(5)" ::: "memory");
        } else {
            asm volatile("s_waitcnt vmcnt(0)" ::: "memory");
        }
        __builtin_amdgcn_s_barrier();          // batch kt resident for ALL waves
        __builtin_amdgcn_sched_barrier(0);     // keep C below the barrier

        // --- C: compute on tile kt ----------------------------------------
        const unsigned long long mwq = mw_cur >> (quad * 4);

        f32x4 st[4];
        #pragma unroll
        for (int ni = 0; ni < 4; ++ni) st[ni] = f32x4{0.f, 0.f, 0.f, 0.f};
        {
            bf16x8 kb[4];
            #pragma unroll
            for (int ni = 0; ni < 4; ++ni)
                kb[ni] = *(const bf16x8*)&Ks[cur][(ni * 16 + l15) * 64 + swz0];
            __builtin_amdgcn_s_setprio(1);
            #pragma unroll
            for (int ni = 0; ni < 4; ++ni)
                st[ni] = __builtin_amdgcn_mfma_f32_16x16x32_bf16(kb[ni], qf[0], st[ni], 0, 0, 0);
            __builtin_amdgcn_s_setprio(0);
            #pragma unroll
            for (int ni = 0; ni < 4; ++ni)
                kb[ni] = *(const bf16x8*)&Ks[cur][(ni * 16 + l15) * 64 + swz1];
            __builtin_amdgcn_s_setprio(1);
            #pragma unroll
            for (int ni = 0; ni < 4; ++ni)
                st[ni] = __builtin_amdgcn_mfma_f32_16x16x32_bf16(kb[ni], qf[1], st[ni], 0, 0, 0);
            __builtin_amdgcn_s_setprio(0);
        }

        // softmax numerator -> P (bf16), packed via v_cvt_pk_bf16_f32
        #pragma unroll
        for (int ni = 0; ni < 4; ++ni) {
            const unsigned int b4 = (unsigned int)(mwq >> (ni * 16)) & 0xFu;
            float p0 = (b4 & 1u) ? fast_exp2(st[ni][0]) : 1.0f;
            float p1 = (b4 & 2u) ? fast_exp2(st[ni][1]) : 1.0f;
            float p2 = (b4 & 4u) ? fast_exp2(st[ni][2]) : 1.0f;
            float p3 = (b4 & 8u) ? fast_exp2(st[ni][3]) : 1.0f;
            *(uint2*)&Ps[w][wadr[ni]] = make_uint2(cvt_pk_bf16(p0, p1), cvt_pk_bf16(p2, p3));
        }

        // PV + row-sum (ones trick)
        {
            bf16x8 pa = *(const bf16x8*)&Ps[w][padr0];
            bf16x8 vb[4];
            #pragma unroll
            for (int nd = 0; nd < 4; ++nd)
                vb[nd] = *(const bf16x8*)&Vs[cur][(nd * 16 + l15) * 64 + swz0];
            __builtin_amdgcn_s_setprio(1);
            l_acc = __builtin_amdgcn_mfma_f32_16x16x32_bf16(pa, onesf, l_acc, 0, 0, 0);
            #pragma unroll
            for (int nd = 0; nd < 4; ++nd)
                o_acc[nd] = __builtin_amdgcn_mfma_f32_16x16x32_bf16(pa, vb[nd], o_acc[nd], 0, 0, 0);
            __builtin_amdgcn_s_setprio(0);

            pa = *(const bf16x8*)&Ps[w][padr1];
            #pragma unroll
            for (int nd = 0; nd < 4; ++nd)
                vb[nd] = *(const bf16x8*)&Vs[cur][(nd * 16 + l15) * 64 + swz1];
            __builtin_amdgcn_s_setprio(1);
            l_acc = __builtin_amdgcn_mfma_f32_16x16x32_bf16(pa, onesf, l_acc, 0, 0, 0);
            #pragma unroll
            for (int nd = 0; nd < 4; ++nd)
                o_acc[nd] = __builtin_amdgcn_mfma_f32_16x16x32_bf16(pa, vb[nd], o_acc[nd], 0, 0, 0);
            __builtin_amdgcn_s_setprio(0);
        }

        mw_cur = mw_nxt;

        // --- D: all reads of buf[cur] done before next A overwrites it ----
        __builtin_amdgcn_s_barrier();
        __builtin_amdgcn_sched_barrier(0);     // pin next A below this barrier
    }

    #pragma unroll
    for (int r = 0; r < 4; ++r) {
        float rinv = 1.0f / l_acc[r];
        int row = q0 + w * 16 + quad * 4 + r;
        #pragma unroll
        for (int nd = 0; nd < 4; ++nd)
            Om[((size_t)b * SEQ + row) * HID + h * DKK + nd * 16 + l15] =
                f32_bf16(o_acc[nd][r] * rinv);
    }
}

// ---------------------------------------------------------------------------
// Kernel 3: out = Om @ Wo^T + bo (fp32 out).  128x64 tiles, round-4 verified
// double-buffer single-barrier K-loop.
// ---------------------------------------------------------------------------
__global__ __launch_bounds__(256, 2)
void outproj_kernel(const unsigned short* __restrict__ Om, const unsigned short* __restrict__ Wob,
                    const float* __restrict__ bo_, float* __restrict__ out)
{
    const int m0 = blockIdx.x * 128;
    const int n0 = blockIdx.y * 64;
    const int tid  = threadIdx.x;
    const int lane = tid & 63, wid = tid >> 6;
    const int wm = (wid >> 1) * 64, wn = (wid & 1) * 32;
    const int l15 = lane & 15, quad = lane >> 4;

    __shared__ __align__(16) unsigned short As[2][128 * 32];   // 2 x 8 KB
    __shared__ __align__(16) unsigned short Bs[2][64 * 32];    // 2 x 4 KB

    const int r0 = tid >> 2, cg = tid & 3;
    const unsigned short* gA = Om + (size_t)(m0 + r0) * HID + ((cg ^ (r0 & 3)) * 8);
    const unsigned short* gB = Wob + (size_t)(n0 + r0) * HID + ((cg ^ (r0 & 3)) * 8);
    const int cgsel = (quad ^ (l15 & 3)) * 8;

    f32x4 acc[4][2];
    #pragma unroll
    for (int i = 0; i < 4; ++i)
        #pragma unroll
        for (int j = 0; j < 2; ++j)
            acc[i][j] = f32x4{0.f, 0.f, 0.f, 0.f};

    // prologue: stage k0=0
    glds16(gA, &As[0][tid * 8]);
    glds16(gA + (size_t)64 * HID, &As[0][(tid + 256) * 8]);
    glds16(gB, &Bs[0][tid * 8]);
    __syncthreads();

    for (int k0 = 0; k0 < HID; k0 += 32) {
        const int cur = (k0 >> 5) & 1;
        if (k0 + 32 < HID) {
            const int nb = cur ^ 1;
            glds16(gA + k0 + 32, &As[nb][tid * 8]);
            glds16(gA + (size_t)64 * HID + k0 + 32, &As[nb][(tid + 256) * 8]);
            glds16(gB + k0 + 32, &Bs[nb][tid * 8]);
        }

        bf16x8 af[4], bfr[2];
        #pragma unroll
        for (int mi = 0; mi < 4; ++mi)
            af[mi] = *(const bf16x8*)&As[cur][(wm + mi * 16 + l15) * 32 + cgsel];
        #pragma unroll
        for (int ni = 0; ni < 2; ++ni)
            bfr[ni] = *(const bf16x8*)&Bs[cur][(wn + ni * 16 + l15) * 32 + cgsel];
        __builtin_amdgcn_s_setprio(1);
        #pragma unroll
        for (int mi = 0; mi < 4; ++mi)
            #pragma unroll
            for (int ni = 0; ni < 2; ++ni)
                acc[mi][ni] = __builtin_amdgcn_mfma_f32_16x16x32_bf16(
                    af[mi], bfr[ni], acc[mi][ni], 0, 0, 0);
        __builtin_amdgcn_s_setprio(0);
        __syncthreads();
    }

    #pragma unroll
    for (int mi = 0; mi < 4; ++mi) {
        #pragma unroll
        for (int ni = 0; ni < 2; ++ni) {
            int n = n0 + wn + ni * 16 + l15;
            float bv = bo_[n];
            #pragma unroll
            for (int r = 0; r < 4; ++r) {
                int m = m0 + wm + mi * 16 + quad * 4 + r;
                out[(size_t)m * HID + n] = acc[mi][ni][r] + bv;
            }
        }
    }
}

// ---------------------------------------------------------------------------
extern "C" void kernel_launch(void* const* d_in, const int* in_sizes, int n_in,
                              void* d_out, int out_size, void* d_ws, size_t ws_size,
                              hipStream_t stream) {
    const float* q    = (const float*)d_in[0];
    const float* k    = (const float*)d_in[1];
    const float* v    = (const float*)d_in[2];
    const int*   mask = (const int*)  d_in[3];
    const float* Wq   = (const float*)d_in[4];
    const float* bq   = (const float*)d_in[5];
    const float* Wk   = (const float*)d_in[6];
    const float* bk   = (const float*)d_in[7];
    const float* Wv   = (const float*)d_in[8];
    const float* bv   = (const float*)d_in[9];
    const float* Wo   = (const float*)d_in[10];
    const float* bo   = (const float*)d_in[11];
    float* out = (float*)d_out;

    // workspace layout (bf16 element offsets):
    unsigned short* ws  = (unsigned short*)d_ws;
    unsigned short* qb  = ws;                  // 4194304 elems (B*S*H)
    unsigned short* kbx = ws + 4194304;
    unsigned short* vbx = ws + 8388608;
    unsigned short* Wqb = ws + 12582912;       // 1048576 elems each
    unsigned short* Wkb = ws + 13631488;
    unsigned short* Wvb = ws + 14680064;
    unsigned short* Wob = ws + 15728640;
    unsigned short* Qh  = ws + 16777216;
    unsigned short* Kh  = ws + 20971520;
    unsigned short* Vt  = ws + 25165824;
    unsigned short* Om  = ws;                  // alias qb (dead after proj)
    unsigned long long* Mb = (unsigned long long*)(ws + 29360128);  // 1 MB
    unsigned short* Vh  = (unsigned short*)d_out;  // scratch: out dead until outproj

    prep_kernel<<<dim3(16896), 256, 0, stream>>>(q, k, v, Wq, Wk, Wv, Wo, mask, ws, Mb);

    proj_kernel<<<dim3(32, 8, 3), 256, 0, stream>>>(qb, kbx, vbx, Wqb, Wkb, Wvb,
                                                    bq, bk, bv, Qh, Kh, Vh);
    vtrans_kernel<<<dim3(32, 32), 256, 0, stream>>>(Vh, Vt);
    attn_kernel<<<dim3(1024), 256, 0, stream>>>(Qh, Kh, Vt, Mb, Om);
    outproj_kernel<<<dim3(32, 16), 256, 0, stream>>>(Om, Wob, bo, out);
}

// Round 9
// 276.967 us; speedup vs baseline: 1.0885x; 1.0318x over previous
//
#include <hip/hip_runtime.h>

#define SEQ   2048
#define NHEAD 16
#define DKK   64
#define HID   1024

typedef __attribute__((ext_vector_type(8))) short bf16x8;
typedef __attribute__((ext_vector_type(4))) float f32x4;

__device__ __forceinline__ unsigned short f32_bf16(float f) {
    unsigned int u = __builtin_bit_cast(unsigned int, f);
    u += 0x7fffu + ((u >> 16) & 1u);
    return (unsigned short)(u >> 16);
}

// one-instruction packed f32x2 -> bf16x2 (RNE), per T12 recipe
__device__ __forceinline__ unsigned int cvt_pk_bf16(float lo, float hi) {
    unsigned int r;
    asm("v_cvt_pk_bf16_f32 %0, %1, %2" : "=v"(r) : "v"(lo), "v"(hi));
    return r;
}

// raw v_exp_f32 (2^x). Scores bounded (|x| < ~45), no range reduction needed.
__device__ __forceinline__ float fast_exp2(float x) {
    float r;
    asm("v_exp_f32 %0, %1" : "=v"(r) : "v"(x));
    return r;
}

// async global->LDS 16B copy (DMA, no VGPR round-trip)
__device__ __forceinline__ void glds16(const void* g, void* l) {
    __builtin_amdgcn_global_load_lds(
        (const __attribute__((address_space(1))) unsigned int*)g,
        (__attribute__((address_space(3))) unsigned int*)l, 16, 0, 0);
}

// ---------------------------------------------------------------------------
// Kernel A: fused prep — fp32->bf16 convert of all 7 tensors + mask bit-pack
// (R4-verified int4 mask form; ballot variant measured slower).
// ---------------------------------------------------------------------------
__global__ __launch_bounds__(256)
void prep_kernel(const float* __restrict__ q, const float* __restrict__ k,
                 const float* __restrict__ v,
                 const float* __restrict__ Wq, const float* __restrict__ Wk,
                 const float* __restrict__ Wv, const float* __restrict__ Wo,
                 const int* __restrict__ mask,
                 unsigned short* __restrict__ ws, unsigned long long* __restrict__ Mb)
{
    const int bid = blockIdx.x;
    if (bid < 16384) {
        int i = bid * 256 + threadIdx.x;            // float4 index
        const float* src; int off;
        if (i < 1048576)      { src = q;  off = i; }
        else if (i < 2097152) { src = k;  off = i - 1048576; }
        else if (i < 3145728) { src = v;  off = i - 2097152; }
        else if (i < 3407872) { src = Wq; off = i - 3145728; }
        else if (i < 3670016) { src = Wk; off = i - 3407872; }
        else if (i < 3932160) { src = Wv; off = i - 3670016; }
        else                  { src = Wo; off = i - 3932160; }
        float4 a = ((const float4*)src)[off];
        ((uint2*)ws)[i] = make_uint2(cvt_pk_bf16(a.x, a.y), cvt_pk_bf16(a.z, a.w));
    } else {
        int idx = (bid - 16384) * 256 + threadIdx.x;
        const int* src = mask + (size_t)idx * 64;
        unsigned long long wv = 0;
        #pragma unroll
        for (int i = 0; i < 16; ++i) {
            int4 m4 = *(const int4*)(src + i * 4);
            wv |= (unsigned long long)(m4.x != 0) << (i * 4 + 0);
            wv |= (unsigned long long)(m4.y != 0) << (i * 4 + 1);
            wv |= (unsigned long long)(m4.z != 0) << (i * 4 + 2);
            wv |= (unsigned long long)(m4.w != 0) << (i * 4 + 3);
        }
        Mb[idx] = wv;
    }
}

// ---------------------------------------------------------------------------
// Kernel 1: QKV projections.  R4-verified double-buffer loop.
// Changes this round:
//  - __launch_bounds__(256,3): grid is 768 = exactly 3 blocks/CU; (256,2)
//    allowed VGPR>170 -> 2 blocks/CU -> 1.5 dispatch rounds (33% tail).
//    Cap guarantees single-round co-residency (acc ~120-150 VGPR, no spill).
//  - z=2 (V): vtrans kernel FUSED into the epilogue.  The 128x128 output
//    tile is transposed in-block through LDS (reusing the dead 32 KB As/Bs
//    staging space) and written directly to Vt[b,h,d,s] coalesced
//    (16 threads/row -> 256 B contiguous segments).
//  LDS swizzle (both phases): ushort (row,col) at
//    SH[row*128 + ((col>>3)^(row&15))*8 + (col&7)]
//  write phase ~2-way conflicts, read phase ~8-way; epilogue-only (~2 us).
// ---------------------------------------------------------------------------
__global__ __launch_bounds__(256, 3)
void proj_kernel(const unsigned short* __restrict__ xq, const unsigned short* __restrict__ xk,
                 const unsigned short* __restrict__ xv,
                 const unsigned short* __restrict__ Wqb, const unsigned short* __restrict__ Wkb,
                 const unsigned short* __restrict__ Wvb,
                 const float* __restrict__ bq_, const float* __restrict__ bk_,
                 const float* __restrict__ bv_,
                 unsigned short* __restrict__ Qh, unsigned short* __restrict__ Kh,
                 unsigned short* __restrict__ Vt)
{
    const int z = blockIdx.z;
    const unsigned short* X; const unsigned short* W; const float* bias;
    if (z == 0)      { X = xq; W = Wqb; bias = bq_; }
    else if (z == 1) { X = xk; W = Wkb; bias = bk_; }
    else             { X = xv; W = Wvb; bias = bv_; }

    const int m0 = blockIdx.x * 128;
    const int n0 = blockIdx.y * 128;
    const int tid  = threadIdx.x;
    const int lane = tid & 63, wid = tid >> 6;
    const int wm = (wid >> 1) * 64, wn = (wid & 1) * 64;
    const int l15 = lane & 15, quad = lane >> 4;

    // unified 32 KB: As = SH[0..8191] (2 bufs x 4096), Bs = SH[8192..16383];
    // reused as the 128x128 ushort transpose tile T after the K-loop (z=2).
    __shared__ __align__(16) unsigned short SH[16384];
    unsigned short* As = SH;
    unsigned short* Bs = SH + 8192;

    const int r0 = tid >> 2, cg = tid & 3;
    const unsigned short* gA = X + (size_t)(m0 + r0) * HID + ((cg ^ (r0 & 3)) * 8);
    const unsigned short* gB = W + (size_t)(n0 + r0) * HID + ((cg ^ (r0 & 3)) * 8);

    const int cgsel = (quad ^ (l15 & 3)) * 8;

    f32x4 acc[4][4];
    #pragma unroll
    for (int i = 0; i < 4; ++i)
        #pragma unroll
        for (int j = 0; j < 4; ++j)
            acc[i][j] = f32x4{0.f, 0.f, 0.f, 0.f};

    // prologue: stage k0=0 into buf 0
    glds16(gA, &As[tid * 8]);
    glds16(gA + (size_t)64 * HID, &As[(tid + 256) * 8]);
    glds16(gB, &Bs[tid * 8]);
    glds16(gB + (size_t)64 * HID, &Bs[(tid + 256) * 8]);
    __syncthreads();

    for (int k0 = 0; k0 < HID; k0 += 32) {
        const int cur = ((k0 >> 5) & 1) * 4096;
        if (k0 + 32 < HID) {                       // prefetch next K-step
            const int nb = (((k0 >> 5) & 1) ^ 1) * 4096;
            glds16(gA + k0 + 32, &As[nb + tid * 8]);
            glds16(gA + (size_t)64 * HID + k0 + 32, &As[nb + (tid + 256) * 8]);
            glds16(gB + k0 + 32, &Bs[nb + tid * 8]);
            glds16(gB + (size_t)64 * HID + k0 + 32, &Bs[nb + (tid + 256) * 8]);
        }

        bf16x8 af[4], bfr[4];
        #pragma unroll
        for (int mi = 0; mi < 4; ++mi)
            af[mi] = *(const bf16x8*)&As[cur + (wm + mi * 16 + l15) * 32 + cgsel];
        #pragma unroll
        for (int ni = 0; ni < 4; ++ni)
            bfr[ni] = *(const bf16x8*)&Bs[cur + (wn + ni * 16 + l15) * 32 + cgsel];
        __builtin_amdgcn_s_setprio(1);
        #pragma unroll
        for (int mi = 0; mi < 4; ++mi)
            #pragma unroll
            for (int ni = 0; ni < 4; ++ni)
                acc[mi][ni] = __builtin_amdgcn_mfma_f32_16x16x32_bf16(
                    af[mi], bfr[ni], acc[mi][ni], 0, 0, 0);
        __builtin_amdgcn_s_setprio(0);
        __syncthreads();                           // reads done + prefetch drained
    }

    if (z == 2) {
        // ---- fused V transpose: acc -> T (swizzled) -> Vt[d][s] coalesced --
        #pragma unroll
        for (int mi = 0; mi < 4; ++mi) {
            #pragma unroll
            for (int ni = 0; ni < 4; ++ni) {
                int ncol = wn + ni * 16 + l15;
                float bv = bias[n0 + ncol];
                #pragma unroll
                for (int r = 0; r < 4; ++r) {
                    int row = wm + mi * 16 + quad * 4 + r;
                    SH[row * 128 + (((ncol >> 3) ^ (row & 15)) * 8) + (ncol & 7)] =
                        f32_bf16(acc[mi][ni][r] + bv);
                }
            }
        }
        __syncthreads();
        const int bb = m0 >> 11, sg0 = m0 & 2047;
        #pragma unroll
        for (int jj = 0; jj < 8; ++jj) {
            int idx = tid + jj * 256;
            int colr = idx >> 4, ch = idx & 15;
            int n = n0 + colr, hh = n >> 6, d = n & 63;
            unsigned short v8[8];
            #pragma unroll
            for (int e = 0; e < 8; ++e) {
                int s = ch * 8 + e;
                v8[e] = SH[s * 128 + (((colr >> 3) ^ (s & 15)) * 8) + (colr & 7)];
            }
            uint4 ov;
            ov.x = (unsigned)v8[0] | ((unsigned)v8[1] << 16);
            ov.y = (unsigned)v8[2] | ((unsigned)v8[3] << 16);
            ov.z = (unsigned)v8[4] | ((unsigned)v8[5] << 16);
            ov.w = (unsigned)v8[6] | ((unsigned)v8[7] << 16);
            *(uint4*)(Vt + (((size_t)(bb * NHEAD + hh) * DKK + d) * SEQ + sg0 + ch * 8)) = ov;
        }
        return;
    }

    const float QSCALE = 0.18033688f;   // 0.125 * log2(e)
    #pragma unroll
    for (int mi = 0; mi < 4; ++mi) {
        #pragma unroll
        for (int ni = 0; ni < 4; ++ni) {
            int n = n0 + wn + ni * 16 + l15;
            float bv = bias[n];
            int hh = n >> 6, d = n & 63;
            #pragma unroll
            for (int r = 0; r < 4; ++r) {
                int m = m0 + wm + mi * 16 + quad * 4 + r;
                int bb = m >> 11, s = m & 2047;
                float val = acc[mi][ni][r] + bv;
                if (z == 0)
                    Qh[((size_t)(bb * NHEAD + hh) * SEQ + s) * DKK + d] = f32_bf16(val * QSCALE);
                else
                    Kh[((size_t)(bb * NHEAD + hh) * SEQ + s) * DKK + d] = f32_bf16(val);
            }
        }
    }
}

// ---------------------------------------------------------------------------
// Kernel 2: flash attention (R8-verified: swapped-QK^T, QBLK=64, counted
// vmcnt(5) pipeline, XCD-aware block remap).  Unchanged.
// ---------------------------------------------------------------------------
__global__ __launch_bounds__(256, 4)
void attn_kernel(const unsigned short* __restrict__ Qh, const unsigned short* __restrict__ Kh,
                 const unsigned short* __restrict__ Vt,
                 const unsigned long long* __restrict__ Mb,
                 unsigned short* __restrict__ Om)
{
    // XCD-aware decode: flat%8 = XCD (round-robin dispatch, m09/T1)
    const int flat = blockIdx.x;           // 0..1023
    const int xcd  = flat & 7;
    const int rest = flat >> 3;
    const int qt   = rest & 31;
    const int g    = rest >> 5;            // 0..3
    const int hb   = g * 8 + xcd;          // 0..31
    const int h    = hb & 15;
    const int b    = hb >> 4;

    const int tid  = threadIdx.x;
    const int lane = tid & 63, w = tid >> 6;
    const int l15 = lane & 15, quad = lane >> 4;
    const int q0 = qt * 64;

    const size_t hoff = (size_t)(b * NHEAD + h) * SEQ * DKK;
    const unsigned short* Qp = Qh + hoff;
    const unsigned short* Kp = Kh + hoff;
    const unsigned short* Vp = Vt + hoff;   // [d][s]

    __shared__ __align__(16) unsigned short Ks[2][64 * 64];
    __shared__ __align__(16) unsigned short Vs[2][64 * 64];
    __shared__ __align__(16) unsigned short Ps[4][16 * 64];

    const int sr0 = tid >> 3, ss0 = tid & 7;
    const int sr1 = sr0 + 32;
    const unsigned short* Kg0 = Kp + sr0 * DKK + ((ss0 ^ (sr0 & 7)) * 8);
    const unsigned short* Kg1 = Kp + sr1 * DKK + ((ss0 ^ (sr1 & 7)) * 8);
    const unsigned short* Vg0 = Vp + (size_t)sr0 * SEQ + ((ss0 ^ (sr0 & 7)) * 8);
    const unsigned short* Vg1 = Vp + (size_t)sr1 * SEQ + ((ss0 ^ (sr1 & 7)) * 8);

    const int swz0 = ((0 * 4 + quad) ^ (l15 & 7)) * 8;
    const int swz1 = ((1 * 4 + quad) ^ (l15 & 7)) * 8;

    const int xsw = l15 & 14;
    int wadr[4];
    #pragma unroll
    for (int ni = 0; ni < 4; ++ni)
        wadr[ni] = l15 * 64 + (((ni * 4 + quad) ^ xsw) * 4);
    const int padr0 = l15 * 64 + (((quad * 2) ^ xsw) * 4);
    const int padr1 = l15 * 64 + (((8 + quad * 2) ^ xsw) * 4);

    // prologue: issue tile 0 (4 DMA); Q frags + mask word ride the same queue
    glds16(Kg0, &Ks[0][tid * 8]);
    glds16(Kg1, &Ks[0][2048 + tid * 8]);
    glds16(Vg0, &Vs[0][tid * 8]);
    glds16(Vg1, &Vs[0][2048 + tid * 8]);

    bf16x8 qf[2];
    #pragma unroll
    for (int kc = 0; kc < 2; ++kc)
        qf[kc] = *(const bf16x8*)(Qp + (size_t)(q0 + w * 16 + l15) * DKK + kc * 32 + quad * 8);

    bf16x8 onesf;
    #pragma unroll
    for (int i = 0; i < 8; ++i) onesf[i] = (short)0x3F80;

    f32x4 o_acc[4];
    f32x4 l_acc = f32x4{0.f, 0.f, 0.f, 0.f};
    #pragma unroll
    for (int nd = 0; nd < 4; ++nd) o_acc[nd] = f32x4{0.f, 0.f, 0.f, 0.f};

    const unsigned long long* Mrow =
        Mb + ((size_t)b * SEQ + q0 + w * 16 + l15) * (SEQ / 64);
    unsigned long long mw_cur = Mrow[0];

    for (int kt = 0; kt < SEQ / 64; ++kt) {
        const int cur = kt & 1;
        unsigned long long mw_nxt = 0ull;

        // --- A: issue next batch (exactly 5 vm ops when taken) ------------
        if (kt < SEQ / 64 - 1) {
            const int nb = cur ^ 1;
            glds16(Kg0 + (kt + 1) * 64 * DKK, &Ks[nb][tid * 8]);
            glds16(Kg1 + (kt + 1) * 64 * DKK, &Ks[nb][2048 + tid * 8]);
            glds16(Vg0 + (kt + 1) * 64,       &Vs[nb][tid * 8]);
            glds16(Vg1 + (kt + 1) * 64,       &Vs[nb][2048 + tid * 8]);
            mw_nxt = Mrow[kt + 1];
            // --- B: wait only batch kt (all but the 5 newest), then join --
            asm volatile("s_waitcnt vmcnt(5)" ::: "memory");
        } else {
            asm volatile("s_waitcnt vmcnt(0)" ::: "memory");
        }
        __builtin_amdgcn_s_barrier();          // batch kt resident for ALL waves
        __builtin_amdgcn_sched_barrier(0);     // keep C below the barrier

        // --- C: compute on tile kt ----------------------------------------
        const unsigned long long mwq = mw_cur >> (quad * 4);

        f32x4 st[4];
        #pragma unroll
        for (int ni = 0; ni < 4; ++ni) st[ni] = f32x4{0.f, 0.f, 0.f, 0.f};
        {
            bf16x8 kb[4];
            #pragma unroll
            for (int ni = 0; ni < 4; ++ni)
                kb[ni] = *(const bf16x8*)&Ks[cur][(ni * 16 + l15) * 64 + swz0];
            __builtin_amdgcn_s_setprio(1);
            #pragma unroll
            for (int ni = 0; ni < 4; ++ni)
                st[ni] = __builtin_amdgcn_mfma_f32_16x16x32_bf16(kb[ni], qf[0], st[ni], 0, 0, 0);
            __builtin_amdgcn_s_setprio(0);
            #pragma unroll
            for (int ni = 0; ni < 4; ++ni)
                kb[ni] = *(const bf16x8*)&Ks[cur][(ni * 16 + l15) * 64 + swz1];
            __builtin_amdgcn_s_setprio(1);
            #pragma unroll
            for (int ni = 0; ni < 4; ++ni)
                st[ni] = __builtin_amdgcn_mfma_f32_16x16x32_bf16(kb[ni], qf[1], st[ni], 0, 0, 0);
            __builtin_amdgcn_s_setprio(0);
        }

        // softmax numerator -> P (bf16), packed via v_cvt_pk_bf16_f32
        #pragma unroll
        for (int ni = 0; ni < 4; ++ni) {
            const unsigned int b4 = (unsigned int)(mwq >> (ni * 16)) & 0xFu;
            float p0 = (b4 & 1u) ? fast_exp2(st[ni][0]) : 1.0f;
            float p1 = (b4 & 2u) ? fast_exp2(st[ni][1]) : 1.0f;
            float p2 = (b4 & 4u) ? fast_exp2(st[ni][2]) : 1.0f;
            float p3 = (b4 & 8u) ? fast_exp2(st[ni][3]) : 1.0f;
            *(uint2*)&Ps[w][wadr[ni]] = make_uint2(cvt_pk_bf16(p0, p1), cvt_pk_bf16(p2, p3));
        }

        // PV + row-sum (ones trick)
        {
            bf16x8 pa = *(const bf16x8*)&Ps[w][padr0];
            bf16x8 vb[4];
            #pragma unroll
            for (int nd = 0; nd < 4; ++nd)
                vb[nd] = *(const bf16x8*)&Vs[cur][(nd * 16 + l15) * 64 + swz0];
            __builtin_amdgcn_s_setprio(1);
            l_acc = __builtin_amdgcn_mfma_f32_16x16x32_bf16(pa, onesf, l_acc, 0, 0, 0);
            #pragma unroll
            for (int nd = 0; nd < 4; ++nd)
                o_acc[nd] = __builtin_amdgcn_mfma_f32_16x16x32_bf16(pa, vb[nd], o_acc[nd], 0, 0, 0);
            __builtin_amdgcn_s_setprio(0);

            pa = *(const bf16x8*)&Ps[w][padr1];
            #pragma unroll
            for (int nd = 0; nd < 4; ++nd)
                vb[nd] = *(const bf16x8*)&Vs[cur][(nd * 16 + l15) * 64 + swz1];
            __builtin_amdgcn_s_setprio(1);
            l_acc = __builtin_amdgcn_mfma_f32_16x16x32_bf16(pa, onesf, l_acc, 0, 0, 0);
            #pragma unroll
            for (int nd = 0; nd < 4; ++nd)
                o_acc[nd] = __builtin_amdgcn_mfma_f32_16x16x32_bf16(pa, vb[nd], o_acc[nd], 0, 0, 0);
            __builtin_amdgcn_s_setprio(0);
        }

        mw_cur = mw_nxt;

        // --- D: all reads of buf[cur] done before next A overwrites it ----
        __builtin_amdgcn_s_barrier();
        __builtin_amdgcn_sched_barrier(0);     // pin next A below this barrier
    }

    #pragma unroll
    for (int r = 0; r < 4; ++r) {
        float rinv = 1.0f / l_acc[r];
        int row = q0 + w * 16 + quad * 4 + r;
        #pragma unroll
        for (int nd = 0; nd < 4; ++nd)
            Om[((size_t)b * SEQ + row) * HID + h * DKK + nd * 16 + l15] =
                f32_bf16(o_acc[nd][r] * rinv);
    }
}

// ---------------------------------------------------------------------------
// Kernel 3: out = Om @ Wo^T + bo (fp32 out).  128x64 tiles, round-4 verified
// double-buffer single-barrier K-loop.
// ---------------------------------------------------------------------------
__global__ __launch_bounds__(256, 2)
void outproj_kernel(const unsigned short* __restrict__ Om, const unsigned short* __restrict__ Wob,
                    const float* __restrict__ bo_, float* __restrict__ out)
{
    const int m0 = blockIdx.x * 128;
    const int n0 = blockIdx.y * 64;
    const int tid  = threadIdx.x;
    const int lane = tid & 63, wid = tid >> 6;
    const int wm = (wid >> 1) * 64, wn = (wid & 1) * 32;
    const int l15 = lane & 15, quad = lane >> 4;

    __shared__ __align__(16) unsigned short As[2][128 * 32];   // 2 x 8 KB
    __shared__ __align__(16) unsigned short Bs[2][64 * 32];    // 2 x 4 KB

    const int r0 = tid >> 2, cg = tid & 3;
    const unsigned short* gA = Om + (size_t)(m0 + r0) * HID + ((cg ^ (r0 & 3)) * 8);
    const unsigned short* gB = Wob + (size_t)(n0 + r0) * HID + ((cg ^ (r0 & 3)) * 8);
    const int cgsel = (quad ^ (l15 & 3)) * 8;

    f32x4 acc[4][2];
    #pragma unroll
    for (int i = 0; i < 4; ++i)
        #pragma unroll
        for (int j = 0; j < 2; ++j)
            acc[i][j] = f32x4{0.f, 0.f, 0.f, 0.f};

    // prologue: stage k0=0
    glds16(gA, &As[0][tid * 8]);
    glds16(gA + (size_t)64 * HID, &As[0][(tid + 256) * 8]);
    glds16(gB, &Bs[0][tid * 8]);
    __syncthreads();

    for (int k0 = 0; k0 < HID; k0 += 32) {
        const int cur = (k0 >> 5) & 1;
        if (k0 + 32 < HID) {
            const int nb = cur ^ 1;
            glds16(gA + k0 + 32, &As[nb][tid * 8]);
            glds16(gA + (size_t)64 * HID + k0 + 32, &As[nb][(tid + 256) * 8]);
            glds16(gB + k0 + 32, &Bs[nb][tid * 8]);
        }

        bf16x8 af[4], bfr[2];
        #pragma unroll
        for (int mi = 0; mi < 4; ++mi)
            af[mi] = *(const bf16x8*)&As[cur][(wm + mi * 16 + l15) * 32 + cgsel];
        #pragma unroll
        for (int ni = 0; ni < 2; ++ni)
            bfr[ni] = *(const bf16x8*)&Bs[cur][(wn + ni * 16 + l15) * 32 + cgsel];
        __builtin_amdgcn_s_setprio(1);
        #pragma unroll
        for (int mi = 0; mi < 4; ++mi)
            #pragma unroll
            for (int ni = 0; ni < 2; ++ni)
                acc[mi][ni] = __builtin_amdgcn_mfma_f32_16x16x32_bf16(
                    af[mi], bfr[ni], acc[mi][ni], 0, 0, 0);
        __builtin_amdgcn_s_setprio(0);
        __syncthreads();
    }

    #pragma unroll
    for (int mi = 0; mi < 4; ++mi) {
        #pragma unroll
        for (int ni = 0; ni < 2; ++ni) {
            int n = n0 + wn + ni * 16 + l15;
            float bv = bo_[n];
            #pragma unroll
            for (int r = 0; r < 4; ++r) {
                int m = m0 + wm + mi * 16 + quad * 4 + r;
                out[(size_t)m * HID + n] = acc[mi][ni][r] + bv;
            }
        }
    }
}

// ---------------------------------------------------------------------------
extern "C" void kernel_launch(void* const* d_in, const int* in_sizes, int n_in,
                              void* d_out, int out_size, void* d_ws, size_t ws_size,
                              hipStream_t stream) {
    const float* q    = (const float*)d_in[0];
    const float* k    = (const float*)d_in[1];
    const float* v    = (const float*)d_in[2];
    const int*   mask = (const int*)  d_in[3];
    const float* Wq   = (const float*)d_in[4];
    const float* bq   = (const float*)d_in[5];
    const float* Wk   = (const float*)d_in[6];
    const float* bk   = (const float*)d_in[7];
    const float* Wv   = (const float*)d_in[8];
    const float* bv   = (const float*)d_in[9];
    const float* Wo   = (const float*)d_in[10];
    const float* bo   = (const float*)d_in[11];
    float* out = (float*)d_out;

    // workspace layout (bf16 element offsets):
    unsigned short* ws  = (unsigned short*)d_ws;
    unsigned short* qb  = ws;                  // 4194304 elems (B*S*H)
    unsigned short* kbx = ws + 4194304;
    unsigned short* vbx = ws + 8388608;
    unsigned short* Wqb = ws + 12582912;       // 1048576 elems each
    unsigned short* Wkb = ws + 13631488;
    unsigned short* Wvb = ws + 14680064;
    unsigned short* Wob = ws + 15728640;
    unsigned short* Qh  = ws + 16777216;
    unsigned short* Kh  = ws + 20971520;
    unsigned short* Vt  = ws + 25165824;
    unsigned short* Om  = ws;                  // alias qb (dead after proj)
    unsigned long long* Mb = (unsigned long long*)(ws + 29360128);  // 1 MB

    prep_kernel<<<dim3(16896), 256, 0, stream>>>(q, k, v, Wq, Wk, Wv, Wo, mask, ws, Mb);

    proj_kernel<<<dim3(32, 8, 3), 256, 0, stream>>>(qb, kbx, vbx, Wqb, Wkb, Wvb,
                                                    bq, bk, bv, Qh, Kh, Vt);
    attn_kernel<<<dim3(1024), 256, 0, stream>>>(Qh, Kh, Vt, Mb, Om);
    outproj_kernel<<<dim3(32, 16), 256, 0, stream>>>(Om, Wob, bo, out);
}